// Round 12
// baseline (1184.312 us; speedup 1.0000x reference)
//
#include <hip/hip_runtime.h>
#include <hip/hip_bf16.h>
#include <math.h>
#include <stdint.h>

typedef __hip_bfloat16 bf16;
typedef __attribute__((ext_vector_type(8))) short short8;
typedef __attribute__((ext_vector_type(4))) short short4v;
typedef __attribute__((ext_vector_type(4))) float f32x4;
typedef __attribute__((ext_vector_type(4))) unsigned int uint4v;
union PF { uint4v u; short8 s; };

#define CC 66      // channels = J*DIMS
#define TT 100     // time steps
#define JJ 22      // joints
#define HH 8       // heads
#define HD 64      // head dim
#define EE 512     // embed
#define CPAD 101   // comb stride in k_fused
#define CPD 100    // comb stride (floats) in k_attn2

// global token layouts in ws (zero-padded)
#define SPT_R 112  // spT rows
#define SPT_S 96   // spT stride
#define TP_R 80    // tp rows
#define TP_S 128   // tp stride

// weight section offsets (bf16 elements) inside ws
#define W_STWK 0                    // [512][128]
#define W_STWQ 65536                // [512][96]
#define W_TSWK 114688               // [512][96]
#define W_TSWQ 163840               // [512][128]
#define W_VST  229376               // WtildeT st: [8][80][128]
#define W_VTS  311296               // WtildeT ts: [8][112][96]
#define W_TOTAL 397312

// k_attn2 LDS layout (short offsets), total 81,680 sh = 163,360 B
#define TSPo 0        // spT tokens [112][104] plain
#define TTPo 11648    // tp tokens  [80][128]  swz3
#define K0Z  21888    // K  A0 [80][64]   swz3
#define Q0Z  27008    // Q  A0 [112][64]  swz3
#define V0Z  34176    // VT A0 [80][96]   swz2
#define K1Z  41856    // K  A1 [112][64]  swz3
#define Q1Z  49024    // Q  A1 [80][64]   swz3
#define V1Z  54144    // VT A1 [112][128] swz3
#define CMB  68480    // comb [66][100] floats = 13,200 sh
#define SMEM2 81680

__device__ __forceinline__ bf16 f2b(float v){ return __float2bfloat16(v); }
__device__ __forceinline__ short sb(float v){ __hip_bfloat16 h = __float2bfloat16(v); return *(short*)&h; }
__device__ __forceinline__ unsigned int pk2(float a, float b){
  unsigned short ua = (unsigned short)sb(a), ub = (unsigned short)sb(b);
  return (unsigned int)ua | ((unsigned int)ub << 16);
}

// ---------------------------------------------------------------- k_wprep
__device__ __forceinline__ void tr_body(
    const float* __restrict__ src, bf16* __restrict__ dst,
    int Rsrc, int Csrc, int JP, int IP, int blk, int tid)
{
  int o = blk*256 + tid;
  if (o >= JP*IP) return;
  int j = o / IP, i = o - j*IP;
  float v = (j < Csrc && i < Rsrc) ? src[(long)i*Csrc + j] : 0.f;
  dst[o] = f2b(v);
}

__device__ __forceinline__ void wt_body(
    const float* __restrict__ wv, const float* __restrict__ wo,
    bf16* __restrict__ dst, int OUT, int KDIM, int OP, int KP, int blk, int tid)
{
  int idx = blk*256 + tid;
  if (idx >= 8*OP*KP) return;
  int o = idx % OP;
  int hk = idx / OP;
  int k = hk % KP, h = hk / KP;
  float acc = 0.f;
  if (o < OUT && k < KDIM) {
    const float* wvp = wv + (long)k*EE + h*64;
    const float* wop = wo + (long)(h*64)*OUT + o;
    #pragma unroll 8
    for (int d = 0; d < 64; ++d) acc += wvp[d] * wop[(long)d*OUT];
  }
  dst[(long)h*OP*KP + (long)o*KP + k] = f2b(acc);
}

__global__ __launch_bounds__(256) void k_wprep(
    const float* __restrict__ st_wk, const float* __restrict__ st_wq,
    const float* __restrict__ ts_wk, const float* __restrict__ ts_wq,
    const float* __restrict__ st_wv, const float* __restrict__ st_wo,
    const float* __restrict__ ts_wv, const float* __restrict__ ts_wo,
    const float* __restrict__ st_bo, const float* __restrict__ st_bv,
    const float* __restrict__ ts_bo, const float* __restrict__ ts_bv,
    bf16* __restrict__ wsec, float* __restrict__ bias2)
{
  const int blk = blockIdx.x, tid = threadIdx.x;
  if      (blk <  256) tr_body(st_wk, wsec + W_STWK, TT, EE, EE, 128, blk,      tid);
  else if (blk <  448) tr_body(st_wq, wsec + W_STWQ, CC, EE, EE,  96, blk-256,  tid);
  else if (blk <  640) tr_body(ts_wk, wsec + W_TSWK, CC, EE, EE,  96, blk-448,  tid);
  else if (blk <  896) tr_body(ts_wq, wsec + W_TSWQ, TT, EE, EE, 128, blk-640,  tid);
  else if (blk < 1216) wt_body(st_wv, st_wo, wsec + W_VST, CC, TT,  80, 128, blk-896,  tid);
  else if (blk < 1552) wt_body(ts_wv, ts_wo, wsec + W_VTS, TT, CC, 112,  96, blk-1216, tid);
  else {
    if (tid < 128) {
      int c = tid; float a = 0.f;
      if (c < CC) {
        a = st_bo[c];
        for (int e = 0; e < EE; ++e) a += st_bv[e] * st_wo[(long)e*CC + c];
      }
      bias2[tid] = a;
    } else {
      int t = tid - 128; float a = 0.f;
      if (t < TT) {
        a = ts_bo[t];
        for (int e = 0; e < EE; ++e) a += ts_bv[e] * ts_wo[(long)e*TT + t];
      }
      bias2[tid] = a;
    }
  }
}

// ---------------------------------------------------------------- k_prep
__global__ __launch_bounds__(256) void k_prep(
    const float* __restrict__ x, const float* __restrict__ adj,
    const float* __restrict__ sadj, const float* __restrict__ tmask,
    const float* __restrict__ tadj,
    bf16* __restrict__ spT_all, bf16* __restrict__ tp_all)
{
  __shared__ float s_x[CC*TT];
  __shared__ float s_Mt[TT*TT];
  __shared__ float s_A[JJ*JJ];
  __shared__ float s_dis[JJ];
  const int b = blockIdx.x, tid = threadIdx.x;
  const long bb = (long)b * (CC*TT);

  if (tid < JJ) {
    float dsum = 0.f;
    for (int i = 0; i < JJ; ++i) dsum += adj[tid*JJ + i];
    s_dis[tid] = dsum > 0.f ? rsqrtf(dsum) : 0.f;
  }
  for (int o = tid; o < CC*TT; o += 256) s_x[o] = x[bb + o];
  for (int o = tid; o < TT*TT; o += 256) {
    int f = o / TT, t = o - f*TT;
    s_Mt[t*TT + f] = tadj[o] * tmask[o];
  }
  __syncthreads();
  for (int o = tid; o < JJ*JJ; o += 256) {
    int v = o / JJ, j = o - v*JJ;
    s_A[o] = sadj[o] * adj[o] * s_dis[v] * s_dis[j];
  }
  __syncthreads();

  bf16* spT = spT_all + (long)b * (SPT_R*SPT_S);
  bf16* tp  = tp_all  + (long)b * (TP_R*TP_S);

  // spT[t][c], 4-t blocks with float4 x reads
  for (int o = tid; o < 28*SPT_S; o += 256) {
    int t4 = o / SPT_S, c = o - t4*SPT_S;
    int t = t4*4;
    float ax=0.f, ay=0.f, az=0.f, aw=0.f;
    if (t < TT && c < CC) {
      int v = c/3, dd = c - v*3;
      for (int j = 0; j < JJ; ++j) {
        float av = s_A[v*JJ + j];
        float4 xv = *(const float4*)(s_x + (j*3+dd)*TT + t);
        ax += av*xv.x; ay += av*xv.y; az += av*xv.z; aw += av*xv.w;
      }
    }
    spT[(t  )*SPT_S + c] = f2b(ax);
    spT[(t+1)*SPT_S + c] = f2b(ay);
    spT[(t+2)*SPT_S + c] = f2b(az);
    spT[(t+3)*SPT_S + c] = f2b(aw);
  }
  // tp[n][f], 4-f blocks with float4 Mt reads
  for (int o = tid; o < TP_R*32; o += 256) {
    int n = o >> 5, f4 = o & 31;
    int f = f4*4;
    float ax=0.f, ay=0.f, az=0.f, aw=0.f;
    if (n < CC && f < TT) {
      for (int t = 0; t < TT; ++t) {
        float xv = s_x[n*TT + t];
        float4 w = *(const float4*)(s_Mt + t*TT + f);
        ax += xv*w.x; ay += xv*w.y; az += xv*w.z; aw += xv*w.w;
      }
    }
    short4v pk;
    pk.x = sb(ax); pk.y = sb(ay); pk.z = sb(az); pk.w = sb(aw);
    *(short4v*)(tp + n*TP_S + f) = pk;
  }
}

// ---------------------------------------------------------------- 8-wave builds
// K/Q: m = d (4 tiles, 2 waves each); A-frags (global weights) reg-cached;
// B-operand token reads swizzled by SWBM ((ln&SWBM)<<3 at 8-short grain).
template<int Nt, int KCH, int SA, int SB, int SWBM>
__device__ __forceinline__ void b_kq(
    const short* __restrict__ W, const short* __restrict__ Tok,
    short* __restrict__ Z, const float* __restrict__ rowbias,
    int gw, int ln, int qd)
{
  const int mi = gw & 3;
  const int d0 = mi*16 + qd*4;
  const short* ap = W + (long)(mi*16 + ln)*SA;
  short8 af[KCH];
  #pragma unroll
  for (int kc = 0; kc < KCH; ++kc) af[kc] = *(const short8*)(ap + qd*8 + kc*32);
  float rb0=0.f, rb1=0.f, rb2=0.f, rb3=0.f;
  if (rowbias) { rb0=rowbias[d0]; rb1=rowbias[d0+1]; rb2=rowbias[d0+2]; rb3=rowbias[d0+3]; }
  const int bsw = (ln & SWBM) << 3;
  constexpr int NU = (Nt + 1) / 2;
  #pragma unroll
  for (int u = 0; u < NU; ++u) {
    const int ni = (gw >> 2) + 2*u;
    if (ni < Nt) {
      const int row = ni*16 + ln;
      const short* bp = Tok + (long)row*SB;
      f32x4 acc = {0.f,0.f,0.f,0.f};
      #pragma unroll
      for (int kc = 0; kc < KCH; ++kc)
        acc = __builtin_amdgcn_mfma_f32_16x16x32_bf16(
            af[kc], *(const short8*)(bp + ((qd*8 + kc*32) ^ bsw)), acc, 0,0,0);
      short4v pk;
      pk.x = sb(acc[0]+rb0); pk.y = sb(acc[1]+rb1);
      pk.z = sb(acc[2]+rb2); pk.w = sb(acc[3]+rb3);
      *(short4v*)(Z + row*64 + (d0 ^ ((ln & 7) << 3))) = pk;
    }
  }
}

// VT: wave gw owns kv m-tile gw; A-frags (LDS tokens, swz SWAM) reg-cached;
// B = global weights; Z[out][kv] swizzled by SWZM.
template<int Mt, int Nt, int KCH, int SA, int SWAM, int SB, int SZ, int SWZM>
__device__ __forceinline__ void b_vt(
    const short* __restrict__ Tok, const short* __restrict__ Wv,
    short* __restrict__ Z, int gw, int ln, int qd)
{
  if (gw >= Mt) return;
  const int mi = gw;
  const int k0 = mi*16 + qd*4;
  const int asw = (ln & SWAM) << 3;
  const short* ap = Tok + (long)(mi*16 + ln)*SA;
  short8 af[KCH];
  #pragma unroll
  for (int kc = 0; kc < KCH; ++kc)
    af[kc] = *(const short8*)(ap + ((qd*8 + kc*32) ^ asw));
  #pragma unroll
  for (int ni = 0; ni < Nt; ++ni) {
    const int row = ni*16 + ln;
    const short* bp = Wv + (long)row*SB;
    f32x4 acc = {0.f,0.f,0.f,0.f};
    #pragma unroll
    for (int kc = 0; kc < KCH; ++kc)
      acc = __builtin_amdgcn_mfma_f32_16x16x32_bf16(
          af[kc], *(const short8*)(bp + qd*8 + kc*32), acc, 0,0,0);
    short4v pk;
    pk.x = sb(acc[0]); pk.y = sb(acc[1]); pk.z = sb(acc[2]); pk.w = sb(acc[3]);
    *(short4v*)(Z + row*SZ + (k0 ^ ((ln & SWZM) << 3))) = pk;
  }
}

// ---------------------------------------------------------------- per-head pieces
template<int A>
__device__ __forceinline__ void build_head(
    short* __restrict__ SMEM, const short* __restrict__ wsec,
    const float* __restrict__ bq, int h, int gw, int ln, int qd)
{
  constexpr int MQ  = A ? 5 : 7;
  constexpr int MKV = A ? 7 : 5;
  constexpr int MO  = A ? 7 : 5;
  constexpr int QCH = A ? 4 : 3;
  constexpr int KCH = A ? 3 : 4;
  constexpr int SWQ = A ? 128 : 96;    // wq global stride
  constexpr int SWK = A ? 96 : 128;    // wk global stride
  constexpr int SWV = A ? 96 : 128;    // wvt global stride
  constexpr int STQ = A ? 128 : 104;   // q-token LDS stride
  constexpr int SWQM= A ? 7 : 0;       // q-token swizzle mask
  constexpr int STK = A ? 104 : 128;   // kv-token LDS stride
  constexpr int SWKM= A ? 0 : 7;       // kv-token swizzle mask
  constexpr int VS  = A ? 128 : 96;    // V zone stride
  constexpr int VWM = A ? 7 : 3;       // V zone swizzle mask
  const short* tokq = SMEM + (A ? TTPo : TSPo);
  const short* tokk = SMEM + (A ? TSPo : TTPo);
  short* Z1 = SMEM + (A ? K1Z : K0Z);
  short* Z2 = SMEM + (A ? Q1Z : Q0Z);
  short* Z3 = SMEM + (A ? V1Z : V0Z);
  const short* wkT = wsec + (A ? W_TSWK : W_STWK);
  const short* wqT = wsec + (A ? W_TSWQ : W_STWQ);
  const short* wvt = wsec + (A ? W_VTS  : W_VST);
  const int base = h * HD;
  b_kq<MKV, KCH, SWK, STK, SWKM>(wkT + (long)base*SWK, tokk, Z1, nullptr, gw, ln, qd);
  b_kq<MQ,  QCH, SWQ, STQ, SWQM>(wqT + (long)base*SWQ, tokq, Z2, bq + base, gw, ln, qd);
  b_vt<MKV, MO, KCH, STK, SWKM, SWV, VS, VWM>(tokk, wvt + (long)h*(MO*16*SWV), Z3, gw, ln, qd);
}

template<int A>
__device__ __forceinline__ void chain_head(
    short* __restrict__ SMEM, int gw, int ln, int qd)
{
  constexpr int KVR = A ? 100 : 66;
  constexpr int QROWS = A ? 66 : 100;
  constexpr int OUTD  = A ? 100 : 66;
  constexpr int MQ  = A ? 5 : 7;
  constexpr int MKV = A ? 7 : 5;
  constexpr int MO  = A ? 7 : 5;
  constexpr int PCH = A ? 4 : 3;
  constexpr int VS  = A ? 128 : 96;
  constexpr int VWM = A ? 7 : 3;
  if (gw >= MQ) return;
  const short* Z1 = SMEM + (A ? K1Z : K0Z);
  const short* Z2 = SMEM + (A ? Q1Z : Q0Z);
  const short* Z3 = SMEM + (A ? V1Z : V0Z);
  float* comb = (float*)(SMEM + CMB);
  const int msk = (ln & 7) << 3;
  const int vmsk = (ln & VWM) << 3;

  // S^T = K @ Q^T : lane holds q=ln (within gw tile), kv = ni*16+qd*4+r
  const short* bqp = Z2 + (gw*16 + ln)*64;
  const short8 qf0 = *(const short8*)(bqp + ((qd*8     ) ^ msk));
  const short8 qf1 = *(const short8*)(bqp + ((qd*8 + 32) ^ msk));
  f32x4 s[MKV];
  #pragma unroll
  for (int ni = 0; ni < MKV; ++ni) {
    const short* ap = Z1 + (ni*16 + ln)*64;
    f32x4 acc = {0.f,0.f,0.f,0.f};
    acc = __builtin_amdgcn_mfma_f32_16x16x32_bf16(
        *(const short8*)(ap + ((qd*8     ) ^ msk)), qf0, acc, 0,0,0);
    acc = __builtin_amdgcn_mfma_f32_16x16x32_bf16(
        *(const short8*)(ap + ((qd*8 + 32) ^ msk)), qf1, acc, 0,0,0);
    s[ni] = acc;
  }
  // mask pad kv + scale
  #pragma unroll
  for (int ni = 0; ni < MKV; ++ni) {
    #pragma unroll
    for (int r = 0; r < 4; ++r) {
      const int kv = ni*16 + qd*4 + r;
      s[ni][r] = (kv < KVR) ? s[ni][r]*0.125f : -1e30f;
    }
  }
  // softmax over kv (own regs + shfl_xor 16, 32)
  float mx = -1e30f;
  #pragma unroll
  for (int ni = 0; ni < MKV; ++ni)
    #pragma unroll
    for (int r = 0; r < 4; ++r) mx = fmaxf(mx, s[ni][r]);
  mx = fmaxf(mx, __shfl_xor(mx, 16));
  mx = fmaxf(mx, __shfl_xor(mx, 32));
  float l = 0.f;
  #pragma unroll
  for (int ni = 0; ni < MKV; ++ni)
    #pragma unroll
    for (int r = 0; r < 4; ++r) {
      float p = __expf(s[ni][r] - mx);
      s[ni][r] = p; l += p;
    }
  l += __shfl_xor(l, 16);
  l += __shfl_xor(l, 32);
  const float rs = 1.f / l;
  // pack P rows (bf16 pairs); tiles beyond MKV are zero
  unsigned int plo[2*PCH], phi[2*PCH];
  #pragma unroll
  for (int ni = 0; ni < 2*PCH; ++ni) {
    if (ni < MKV) {
      plo[ni] = pk2(s[ni][0]*rs, s[ni][1]*rs);
      phi[ni] = pk2(s[ni][2]*rs, s[ni][3]*rs);
    } else { plo[ni] = 0u; phi[ni] = 0u; }
  }
  // build B-fragments of P in-register (shfl dance), all PCH kept live
  PF pf[PCH];
  #pragma unroll
  for (int kc = 0; kc < PCH; ++kc) {
    #pragma unroll
    for (int w = 0; w < 4; ++w) {
      const int srcLane = ln + 16*((qd & 1)*2 + (w >> 1));
      int va, vb;
      if (w & 1) {
        va = __shfl((int)phi[2*kc  ], srcLane, 64);
        vb = __shfl((int)phi[2*kc+1], srcLane, 64);
      } else {
        va = __shfl((int)plo[2*kc  ], srcLane, 64);
        vb = __shfl((int)plo[2*kc+1], srcLane, 64);
      }
      pf[kc].u[w] = (qd < 2) ? (unsigned int)va : (unsigned int)vb;
    }
  }
  // PV per out-tile: acc in regs over kc, then ds atomicAdd into comb.
  // atomicAdd makes cross-flavor concurrent accumulation race-free.
  const int q = gw*16 + ln;
  #pragma unroll
  for (int oi = 0; oi < MO; ++oi) {
    const short* ap = Z3 + (oi*16 + ln)*VS;
    f32x4 acc = {0.f,0.f,0.f,0.f};
    #pragma unroll
    for (int kc = 0; kc < PCH; ++kc)
      acc = __builtin_amdgcn_mfma_f32_16x16x32_bf16(
          *(const short8*)(ap + ((qd*8 + kc*32) ^ vmsk)), pf[kc].s, acc, 0,0,0);
    if (q < QROWS) {
      #pragma unroll
      for (int r = 0; r < 4; ++r) {
        const int outc = oi*16 + qd*4 + r;
        if (outc < OUTD) {
          const int idx = A ? (q*CPD + outc) : (outc*CPD + q);
          atomicAdd(&comb[idx], acc[r]);
        }
      }
    }
  }
}

// ---------------------------------------------------------------- k_attn2 (mega)
// 1024 threads: waves 0-7 flavor A=0, waves 8-15 A=1 (concurrent, r6's phase
// structure: 2 barriers/head x 8 heads). PV accumulates into comb LDS via
// ds atomics (no cross-head register accumulator -> no spill at the 64-VGPR
// cap). Tokens staged once; epilogue fused.
__global__ __launch_bounds__(1024) void k_attn2(
    const bf16* __restrict__ spT_all, const bf16* __restrict__ tp_all,
    const bf16* __restrict__ wsec_,
    const float* __restrict__ st_bq, const float* __restrict__ ts_bq,
    const float* __restrict__ bias2, const float* __restrict__ x,
    const float* __restrict__ alpha, const float* __restrict__ beta,
    const float* __restrict__ fcw, const float* __restrict__ fcb,
    float* __restrict__ out)
{
  __shared__ __align__(16) short SMEM[SMEM2];
  const int b = blockIdx.x, tid = threadIdx.x;
  const long bb = (long)b * (CC*TT);
  const int wave = tid >> 6, lane = tid & 63, ln = lane & 15, qd = lane >> 4;
  const int g = wave >> 3, gw = wave & 7;
  const short* wsec = (const short*)wsec_;
  float* comb = (float*)(SMEM + CMB);

  // stage tokens: TSP plain [112][104]; TTP [80][128] with 3-bit XOR swizzle
  {
    const short* gsp = (const short*)(spT_all + (long)b*SPT_R*SPT_S);
    const short* gtp = (const short*)(tp_all  + (long)b*TP_R*TP_S);
    for (int o = tid; o < 112*12; o += 1024) {
      int r = o / 12, c8 = o - r*12;
      *(short8*)(SMEM + TSPo + r*104 + c8*8) = *(const short8*)(gsp + r*SPT_S + c8*8);
    }
    for (int o = tid; o < 80*16; o += 1024) {
      int r = o >> 4, c8 = o & 15;
      *(short8*)(SMEM + TTPo + r*128 + ((c8*8) ^ ((r & 7) << 3))) =
          *(const short8*)(gtp + r*TP_S + c8*8);
    }
    for (int o = tid; o < CC*CPD; o += 1024) comb[o] = 0.f;
  }
  // zero V pad kv-cols (builds never rewrite them; PV reads them as zeros)
  for (int o = tid; o < 80*16; o += 1024) {        // V0: cols [80,96)
    int r = o >> 4, kv = 80 + (o & 15);
    SMEM[V0Z + r*96 + (kv ^ ((r & 3) << 3))] = 0;
  }
  for (int o = tid; o < 112*16; o += 1024) {       // V1: cols [112,128)
    int r = o >> 4, kv = 112 + (o & 15);
    SMEM[V1Z + r*128 + (kv ^ ((r & 7) << 3))] = 0;
  }

  for (int h = 0; h < HH; ++h) {
    __syncthreads();   // staging/pads done (h=0); zone WAR (h>0)
    if (g == 0) build_head<0>(SMEM, wsec, st_bq, h, gw, ln, qd);
    else        build_head<1>(SMEM, wsec, ts_bq, h, gw, ln, qd);
    __syncthreads();
    if (g == 0) chain_head<0>(SMEM, gw, ln, qd);
    else        chain_head<1>(SMEM, gw, ln, qd);
  }

  // ---------------- fused epilogue (zones + tokens dead) ----------------
  float* s_w = (float*)(SMEM + K0Z);   // fcw^T [t][f], 40,000 B over zones
  __syncthreads();
  for (int o = tid; o < TT*TT; o += 1024) {
    int f = o / TT, t = o - f*TT;
    s_w[t*TT + f] = fcw[o];
  }
  // folded output biases
  for (int o = tid; o < CC*TT; o += 1024) {
    int c = o / TT, t = o - c*TT;
    comb[c*CPD + t] += bias2[c] + bias2[128 + t];
  }
  __syncthreads();
  // LN over channels (2 lanes per t) + residual
  if (tid < 2*TT) {
    const int t = tid >> 1, hf = tid & 1;
    float part = 0.f;
    for (int c = hf; c < CC; c += 2) part += comb[c*CPD + t];
    float mean = (part + __shfl_xor(part, 1)) * (1.f/CC);
    float vp = 0.f;
    for (int c = hf; c < CC; c += 2) { float dv = comb[c*CPD + t] - mean; vp += dv*dv; }
    float var = (vp + __shfl_xor(vp, 1)) * (1.f/CC);
    float rstd = 1.f / sqrtf(var + 1e-5f);
    for (int c = hf; c < CC; c += 2) {
      float y = (comb[c*CPD + t] - mean) * rstd * alpha[c] + beta[c];
      comb[c*CPD + t] = y + x[bb + c*TT + t];
    }
  }
  __syncthreads();
  // FC over t (float4 weights) + tanh -> out
  for (int o = tid; o < CC*25; o += 1024) {
    int c = o / 25, f4 = o - c*25;
    int f = f4*4;
    const float* cr = comb + c*CPD;
    float ax=0.f, ay=0.f, az=0.f, aw=0.f;
    for (int t = 0; t < TT; ++t) {
      float xv = cr[t];
      float4 wv = *(const float4*)(s_w + t*TT + f);
      ax += xv*wv.x; ay += xv*wv.y; az += xv*wv.z; aw += xv*wv.w;
    }
    float4 r4;
    r4.x = tanhf(ax + fcb[f  ]); r4.y = tanhf(ay + fcb[f+1]);
    r4.z = tanhf(az + fcb[f+2]); r4.w = tanhf(aw + fcb[f+3]);
    *(float4*)(out + bb + c*TT + f) = r4;
  }
}

// ---------------------------------------------------------------- R4 fallback
__global__ __launch_bounds__(128) void k_fused(
    const float* __restrict__ x, const float* __restrict__ adj,
    const float* __restrict__ sadj, const float* __restrict__ tmask,
    const float* __restrict__ tadj,
    const float* __restrict__ st_wq, const float* __restrict__ st_bq,
    const float* __restrict__ st_wk, const float* __restrict__ st_bk,
    const float* __restrict__ st_wv, const float* __restrict__ st_bv,
    const float* __restrict__ st_wo, const float* __restrict__ st_bo,
    const float* __restrict__ ts_wq, const float* __restrict__ ts_bq,
    const float* __restrict__ ts_wk, const float* __restrict__ ts_bk,
    const float* __restrict__ ts_wv, const float* __restrict__ ts_bv,
    const float* __restrict__ ts_wo, const float* __restrict__ ts_bo,
    const float* __restrict__ alpha, const float* __restrict__ beta,
    const float* __restrict__ fcw, const float* __restrict__ fcb,
    float* __restrict__ out)
{
  __shared__ float s_sp[CC*TT];
  __shared__ float s_tp[CC*TT];
  __shared__ __align__(16) float s_kv[2*TT*HD];
  __shared__ float s_comb[CC*CPAD];
  __shared__ float s_A[JJ*JJ];
  __shared__ float s_dis[JJ];

  const int b = blockIdx.x, tid = threadIdx.x;
  const long bb = (long)b * (CC*TT);
  float* s_xs = s_comb;
  float* s_Mt = s_kv;

  if (tid < JJ) {
    float dsum = 0.f;
    for (int i = 0; i < JJ; ++i) dsum += adj[tid*JJ + i];
    s_dis[tid] = dsum > 0.f ? rsqrtf(dsum) : 0.f;
  }
  for (int o = tid; o < CC*TT; o += 128) s_xs[o] = x[bb + o];
  for (int o = tid; o < TT*TT; o += 128) {
    int f = o / TT, t = o - f*TT;
    s_Mt[t*TT + f] = tadj[o] * tmask[o];
  }
  __syncthreads();
  for (int o = tid; o < JJ*JJ; o += 128) {
    int v = o / JJ, j = o - v*JJ;
    s_A[o] = sadj[o] * adj[o] * s_dis[v] * s_dis[j];
  }
  __syncthreads();

  for (int o = tid; o < CC*TT; o += 128) {
    int c = o / TT, t = o - c*TT, v = c / 3, dd = c - v*3;
    float acc = 0.f;
    for (int j = 0; j < JJ; ++j) acc += s_A[v*JJ + j] * s_xs[(j*3 + dd)*TT + t];
    s_sp[o] = acc;
  }
  for (int o = tid; o < CC*TT; o += 128) {
    int n = o / TT, f = o - n*TT;
    float a0 = 0.f, a1 = 0.f;
    for (int t = 0; t < TT; t += 2) {
      a0 += s_xs[n*TT + t    ] * s_Mt[(t    )*TT + f];
      a1 += s_xs[n*TT + t + 1] * s_Mt[(t + 1)*TT + f];
    }
    s_tp[o] = a0 + a1;
  }
  __syncthreads();

  for (int o = tid; o < CC*TT; o += 128) {
    int c = o / TT, t = o - c*TT;
    s_comb[c*CPAD + t] = st_bo[c] + ts_bo[t];
  }

  {
    float* s_k = s_kv;
    float* s_v = s_kv + TT*HD;
    for (int h = 0; h < HH; ++h) {
      const int base = h*HD;
      __syncthreads();
      {
        const int d = tid & 63, krow = tid >> 6;
        for (int kk = 0; kk < CC/2; ++kk) {
          int k = kk*2 + krow;
          float aK = st_bk[base + d], aV = st_bv[base + d];
          const float* tr = s_tp + k*TT;
          for (int t = 0; t < TT; ++t) {
            float a = tr[t];
            aK += a * st_wk[(long)t*EE + base + d];
            aV += a * st_wv[(long)t*EE + base + d];
          }
          s_k[k*HD + d] = aK;
          s_v[k*HD + d] = aV;
        }
      }
      __syncthreads();
      if (tid < TT) {
        const int q = tid;
        float qv[HD];
        #pragma unroll
        for (int d = 0; d < HD; ++d) qv[d] = st_bq[base + d];
        for (int c = 0; c < CC; ++c) {
          float a = s_sp[c*TT + q];
          const float* wr = st_wq + (long)c*EE + base;
          #pragma unroll
          for (int d = 0; d < HD; ++d) qv[d] += a * wr[d];
        }
        float m = -INFINITY, l = 0.f, ov[HD];
        #pragma unroll
        for (int d = 0; d < HD; ++d) ov[d] = 0.f;
        for (int k = 0; k < CC; ++k) {
          const float4* kr4 = (const float4*)(s_k + k*HD);
          float s0=0.f,s1=0.f,s2=0.f,s3=0.f;
          #pragma unroll
          for (int i = 0; i < 16; ++i) {
            float4 kk4 = kr4[i];
            s0 += qv[4*i  ]*kk4.x; s1 += qv[4*i+1]*kk4.y;
            s2 += qv[4*i+2]*kk4.z; s3 += qv[4*i+3]*kk4.w;
          }
          float s  = (s0+s1+s2+s3) * 0.125f;
          float mn = fmaxf(m, s);
          float corr = __expf(m - mn);
          float p    = __expf(s - mn);
          l = l*corr + p;
          const float4* vr4 = (const float4*)(s_v + k*HD);
          #pragma unroll
          for (int i = 0; i < 16; ++i) {
            float4 vv4 = vr4[i];
            ov[4*i  ] = ov[4*i  ]*corr + p*vv4.x;
            ov[4*i+1] = ov[4*i+1]*corr + p*vv4.y;
            ov[4*i+2] = ov[4*i+2]*corr + p*vv4.z;
            ov[4*i+3] = ov[4*i+3]*corr + p*vv4.w;
          }
          m = mn;
        }
        float rl = 1.f/l;
        #pragma unroll
        for (int d = 0; d < HD; ++d) ov[d] *= rl;
        for (int c = 0; c < CC; ++c) {
          const float* wr = st_wo + (long)base*CC + c;
          float a0=0.f,a1=0.f,a2=0.f,a3=0.f;
          #pragma unroll
          for (int d = 0; d < HD; d += 4) {
            a0 += ov[d  ]*wr[(long)(d  )*CC]; a1 += ov[d+1]*wr[(long)(d+1)*CC];
            a2 += ov[d+2]*wr[(long)(d+2)*CC]; a3 += ov[d+3]*wr[(long)(d+3)*CC];
          }
          s_comb[c*CPAD + q] += a0+a1+a2+a3;
        }
      }
    }
  }

  {
    float* s_k = s_kv;
    float* s_v = s_kv + TT*HD;
    for (int h = 0; h < HH; ++h) {
      const int base = h*HD;
      __syncthreads();
      {
        const int d = tid & 63, krow = tid >> 6;
        for (int kk = 0; kk < TT/2; ++kk) {
          int k = kk*2 + krow;
          float aK = ts_bk[base + d], aV = ts_bv[base + d];
          for (int c = 0; c < CC; ++c) {
            float a = s_sp[c*TT + k];
            aK += a * ts_wk[(long)c*EE + base + d];
            aV += a * ts_wv[(long)c*EE + base + d];
          }
          s_k[k*HD + d] = aK;
          s_v[k*HD + d] = aV;
        }
      }
      __syncthreads();
      if (tid < CC) {
        const int q = tid;
        float qv[HD];
        #pragma unroll
        for (int d = 0; d < HD; ++d) qv[d] = ts_bq[base + d];
        const float* tr = s_tp + q*TT;
        for (int t = 0; t < TT; ++t) {
          float a = tr[t];
          const float* wr = ts_wq + (long)t*EE + base;
          #pragma unroll
          for (int d = 0; d < HD; ++d) qv[d] += a * wr[d];
        }
        float m = -INFINITY, l = 0.f, ov[HD];
        #pragma unroll
        for (int d = 0; d < HD; ++d) ov[d] = 0.f;
        for (int k = 0; k < TT; ++k) {
          const float4* kr4 = (const float4*)(s_k + k*HD);
          float s0=0.f,s1=0.f,s2=0.f,s3=0.f;
          #pragma unroll
          for (int i = 0; i < 16; ++i) {
            float4 kk4 = kr4[i];
            s0 += qv[4*i  ]*kk4.x; s1 += qv[4*i+1]*kk4.y;
            s2 += qv[4*i+2]*kk4.z; s3 += qv[4*i+3]*kk4.w;
          }
          float s  = (s0+s1+s2+s3) * 0.125f;
          float mn = fmaxf(m, s);
          float corr = __expf(m - mn);
          float p    = __expf(s - mn);
          l = l*corr + p;
          const float4* vr4 = (const float4*)(s_v + k*HD);
          #pragma unroll
          for (int i = 0; i < 16; ++i) {
            float4 vv4 = vr4[i];
            ov[4*i  ] = ov[4*i  ]*corr + p*vv4.x;
            ov[4*i+1] = ov[4*i+1]*corr + p*vv4.y;
            ov[4*i+2] = ov[4*i+2]*corr + p*vv4.z;
            ov[4*i+3] = ov[4*i+3]*corr + p*vv4.w;
          }
          m = mn;
        }
        float rl = 1.f/l;
        #pragma unroll
        for (int d = 0; d < HD; ++d) ov[d] *= rl;
        for (int t = 0; t < TT; ++t) {
          const float* wr = ts_wo + (long)base*TT + t;
          float a0=0.f,a1=0.f,a2=0.f,a3=0.f;
          #pragma unroll
          for (int d = 0; d < HD; d += 4) {
            a0 += ov[d  ]*wr[(long)(d  )*TT]; a1 += ov[d+1]*wr[(long)(d+1)*TT];
            a2 += ov[d+2]*wr[(long)(d+2)*TT]; a3 += ov[d+3]*wr[(long)(d+3)*TT];
          }
          s_comb[q*CPAD + t] += a0+a1+a2+a3;
        }
      }
    }
  }
  __syncthreads();

  if (tid < TT) {
    const int t = tid;
    float mean = 0.f;
    for (int c = 0; c < CC; ++c) mean += s_comb[c*CPAD + t];
    mean *= (1.f/CC);
    float var = 0.f;
    for (int c = 0; c < CC; ++c) { float dv = s_comb[c*CPAD + t] - mean; var += dv*dv; }
    var *= (1.f/CC);
    float rstd = 1.f / sqrtf(var + 1e-5f);
    for (int c = 0; c < CC; ++c) {
      float y = (s_comb[c*CPAD + t] - mean) * rstd * alpha[c] + beta[c];
      s_comb[c*CPAD + t] = y + x[bb + c*TT + t];
    }
  }
  __syncthreads();

  float* s_w = s_kv;
  for (int o = tid; o < TT*TT; o += 128) {
    int f = o / TT, t = o - f*TT;
    s_w[t*TT + f] = fcw[o];
  }
  __syncthreads();

  for (int o = tid; o < CC*TT; o += 128) {
    int c = o / TT, f = o - c*TT;
    const float* cr = s_comb + c*CPAD;
    float a0 = 0.f, a1 = 0.f;
    for (int t = 0; t < TT; t += 2) {
      a0 += cr[t    ] * s_w[(t    )*TT + f];
      a1 += cr[t + 1] * s_w[(t + 1)*TT + f];
    }
    out[bb + o] = tanhf(a0 + a1 + fcb[f]);
  }
}

// ---------------------------------------------------------------- launch
extern "C" void kernel_launch(void* const* d_in, const int* in_sizes, int n_in,
                              void* d_out, int out_size, void* d_ws, size_t ws_size,
                              hipStream_t stream) {
  const float* x     = (const float*)d_in[0];
  const float* adj   = (const float*)d_in[1];
  const float* sadj  = (const float*)d_in[2];
  const float* tmask = (const float*)d_in[3];
  const float* tadj  = (const float*)d_in[4];
  const float* st_wq = (const float*)d_in[5];  const float* st_bq = (const float*)d_in[6];
  const float* st_wk = (const float*)d_in[7];  const float* st_bk = (const float*)d_in[8];
  const float* st_wv = (const float*)d_in[9];  const float* st_bv = (const float*)d_in[10];
  const float* st_wo = (const float*)d_in[11]; const float* st_bo = (const float*)d_in[12];
  const float* ts_wq = (const float*)d_in[13]; const float* ts_bq = (const float*)d_in[14];
  const float* ts_wk = (const float*)d_in[15]; const float* ts_bk = (const float*)d_in[16];
  const float* ts_wv = (const float*)d_in[17]; const float* ts_bv = (const float*)d_in[18];
  const float* ts_wo = (const float*)d_in[19]; const float* ts_bo = (const float*)d_in[20];
  const float* alpha = (const float*)d_in[21]; const float* beta  = (const float*)d_in[22];
  const float* fcw   = (const float*)d_in[23]; const float* fcb   = (const float*)d_in[24];
  float* out = (float*)d_out;

  const int B = in_sizes[0] / (CC*TT);
  const size_t w_bytes   = (size_t)W_TOTAL * 2 + 1024;   // + bias2 floats
  const size_t spt_bytes = (size_t)B * SPT_R * SPT_S * 2;
  const size_t tp_bytes  = (size_t)B * TP_R * TP_S * 2;
  const size_t need = w_bytes + spt_bytes + tp_bytes;

  if (ws_size >= need) {
    bf16*  wsec    = (bf16*)d_ws;
    float* bias2   = (float*)((char*)d_ws + (size_t)W_TOTAL*2);
    bf16*  spT_all = (bf16*)((char*)d_ws + w_bytes);
    bf16*  tp_all  = spT_all + (size_t)B * SPT_R * SPT_S;

    k_wprep<<<1553, 256, 0, stream>>>(st_wk, st_wq, ts_wk, ts_wq,
                                      st_wv, st_wo, ts_wv, ts_wo,
                                      st_bo, st_bv, ts_bo, ts_bv,
                                      wsec, bias2);
    k_prep<<<B, 256, 0, stream>>>(x, adj, sadj, tmask, tadj, spT_all, tp_all);
    k_attn2<<<B, 1024, 0, stream>>>(spT_all, tp_all, wsec, st_bq, ts_bq,
                                    bias2, x, alpha, beta, fcw, fcb, out);
  } else {
    k_fused<<<B, 128, 0, stream>>>(x, adj, sadj, tmask, tadj,
                                   st_wq, st_bq, st_wk, st_bk, st_wv, st_bv, st_wo, st_bo,
                                   ts_wq, ts_bq, ts_wk, ts_bk, ts_wv, ts_bv, ts_wo, ts_bo,
                                   alpha, beta, fcw, fcb, out);
  }
}

// Round 13
// 682.106 us; speedup vs baseline: 1.7363x; 1.7363x over previous
//
#include <hip/hip_runtime.h>
#include <hip/hip_bf16.h>
#include <math.h>
#include <stdint.h>

typedef __hip_bfloat16 bf16;
typedef __attribute__((ext_vector_type(8))) short short8;
typedef __attribute__((ext_vector_type(4))) short short4v;
typedef __attribute__((ext_vector_type(4))) float f32x4;
typedef __attribute__((ext_vector_type(4))) unsigned int uint4v;
union PF { uint4v u; short8 s; };

#define CC 66      // channels = J*DIMS
#define TT 100     // time steps
#define JJ 22      // joints
#define HH 8       // heads
#define HD 64      // head dim
#define EE 512     // embed
#define CPAD 101   // comb stride (floats)

// weight section offsets (bf16 elements) inside ws
#define W_STWK 0                    // [512][128]
#define W_STWQ 65536                // [512][96]
#define W_TSWK 114688               // [512][96]
#define W_TSWQ 163840               // [512][128]
#define W_VST  229376               // WtildeT st: [8][80][128]
#define W_VTS  311296               // WtildeT ts: [8][112][96]
#define W_TOTAL 397312

// k_attn2 LDS layout (short offsets)
#define TOKSP 0        // [112][104]      spT tokens (plain)
#define TOKTP 11648    // [80][136]       tp tokens (plain)
#define G0Z1  22528    // K  A0 [80][64]
#define G0Z2  27648    // Q  A0 [112][64]
#define G0Z3  34816    // VT A0 [80][128]
#define G1Z1  45056    // K  A1 [112][64]
#define G1Z2  52224    // Q  A1 [80][64]
#define G1Z3  57344    // VT A1 [112][128]
#define SMEM_SH 71680  // 143,360 B
// prologue staging (overlaps zones; all dead before head loop starts)
#define P_SX  22528    // x [66][100] f32 = 13,200 sh
#define P_SMT 35728    // M^T [100][100] f32 = 20,000 sh
#define P_SA  55728    // A [22][22] f32 = 968 sh
#define P_SDIS 56696   // dis [22] f32 = 44 sh

__device__ __forceinline__ bf16 f2b(float v){ return __float2bfloat16(v); }
__device__ __forceinline__ short sb(float v){ __hip_bfloat16 h = __float2bfloat16(v); return *(short*)&h; }
__device__ __forceinline__ unsigned int pk2(float a, float b){
  unsigned short ua = (unsigned short)sb(a), ub = (unsigned short)sb(b);
  return (unsigned int)ua | ((unsigned int)ub << 16);
}

// ---------------------------------------------------------------- k_wprep
__device__ __forceinline__ void tr_body(
    const float* __restrict__ src, bf16* __restrict__ dst,
    int Rsrc, int Csrc, int JP, int IP, int blk, int tid)
{
  int o = blk*256 + tid;
  if (o >= JP*IP) return;
  int j = o / IP, i = o - j*IP;
  float v = (j < Csrc && i < Rsrc) ? src[(long)i*Csrc + j] : 0.f;
  dst[o] = f2b(v);
}

__device__ __forceinline__ void wt_body(
    const float* __restrict__ wv, const float* __restrict__ wo,
    bf16* __restrict__ dst, int OUT, int KDIM, int OP, int KP, int blk, int tid)
{
  int idx = blk*256 + tid;
  if (idx >= 8*OP*KP) return;
  int o = idx % OP;
  int hk = idx / OP;
  int k = hk % KP, h = hk / KP;
  float acc = 0.f;
  if (o < OUT && k < KDIM) {
    const float* wvp = wv + (long)k*EE + h*64;
    const float* wop = wo + (long)(h*64)*OUT + o;
    #pragma unroll 8
    for (int d = 0; d < 64; ++d) acc += wvp[d] * wop[(long)d*OUT];
  }
  dst[(long)h*OP*KP + (long)o*KP + k] = f2b(acc);
}

__global__ __launch_bounds__(256) void k_wprep(
    const float* __restrict__ st_wk, const float* __restrict__ st_wq,
    const float* __restrict__ ts_wk, const float* __restrict__ ts_wq,
    const float* __restrict__ st_wv, const float* __restrict__ st_wo,
    const float* __restrict__ ts_wv, const float* __restrict__ ts_wo,
    const float* __restrict__ st_bo, const float* __restrict__ st_bv,
    const float* __restrict__ ts_bo, const float* __restrict__ ts_bv,
    bf16* __restrict__ wsec, float* __restrict__ bias2)
{
  const int blk = blockIdx.x, tid = threadIdx.x;
  if      (blk <  256) tr_body(st_wk, wsec + W_STWK, TT, EE, EE, 128, blk,      tid);
  else if (blk <  448) tr_body(st_wq, wsec + W_STWQ, CC, EE, EE,  96, blk-256,  tid);
  else if (blk <  640) tr_body(ts_wk, wsec + W_TSWK, CC, EE, EE,  96, blk-448,  tid);
  else if (blk <  896) tr_body(ts_wq, wsec + W_TSWQ, TT, EE, EE, 128, blk-640,  tid);
  else if (blk < 1216) wt_body(st_wv, st_wo, wsec + W_VST, CC, TT,  80, 128, blk-896,  tid);
  else if (blk < 1552) wt_body(ts_wv, ts_wo, wsec + W_VTS, TT, CC, 112,  96, blk-1216, tid);
  else {
    if (tid < 128) {
      int c = tid; float a = 0.f;
      if (c < CC) {
        a = st_bo[c];
        for (int e = 0; e < EE; ++e) a += st_bv[e] * st_wo[(long)e*CC + c];
      }
      bias2[tid] = a;
    } else {
      int t = tid - 128; float a = 0.f;
      if (t < TT) {
        a = ts_bo[t];
        for (int e = 0; e < EE; ++e) a += ts_bv[e] * ts_wo[(long)e*TT + t];
      }
      bias2[tid] = a;
    }
  }
}

// ---------------------------------------------------------------- builds
// K/Q: m = d (4 tiles, 2 waves each); A-frags (global weights) reg-cached.
template<int Nt, int KCH, int SA, int SB>
__device__ __forceinline__ void build_kq(
    const short* __restrict__ W, const short* __restrict__ Tok,
    short* __restrict__ Z, const float* __restrict__ rowbias,
    int gw, int ln, int qd)
{
  const int mi = gw & 3;
  const int d0 = mi*16 + qd*4;
  const short* ap = W + (long)(mi*16 + ln)*SA;
  short8 af[KCH];
  #pragma unroll
  for (int kc = 0; kc < KCH; ++kc) af[kc] = *(const short8*)(ap + qd*8 + kc*32);
  float rb0=0.f, rb1=0.f, rb2=0.f, rb3=0.f;
  if (rowbias) { rb0=rowbias[d0]; rb1=rowbias[d0+1]; rb2=rowbias[d0+2]; rb3=rowbias[d0+3]; }
  constexpr int NU = (Nt + 1) / 2;
  #pragma unroll
  for (int u = 0; u < NU; ++u) {
    const int ni = (gw >> 2) + 2*u;
    if (ni < Nt) {
      const int row = ni*16 + ln;
      const short* bp = Tok + (long)row*SB;
      f32x4 acc = {0.f,0.f,0.f,0.f};
      #pragma unroll
      for (int kc = 0; kc < KCH; ++kc)
        acc = __builtin_amdgcn_mfma_f32_16x16x32_bf16(
            af[kc], *(const short8*)(bp + qd*8 + kc*32), acc, 0,0,0);
      short4v pk;
      pk.x = sb(acc[0]+rb0); pk.y = sb(acc[1]+rb1);
      pk.z = sb(acc[2]+rb2); pk.w = sb(acc[3]+rb3);
      *(short4v*)(Z + row*64 + (d0 ^ ((ln & 7) << 3))) = pk;
    }
  }
}

// VT: wave gw owns kv m-tile gw; A-frags (LDS tokens) reg-cached.
template<int Mt, int Nt, int KCH, int SA, int SB, int SZ>
__device__ __forceinline__ void build_vt(
    const short* __restrict__ Tok, const short* __restrict__ Wv,
    short* __restrict__ Z, int gw, int ln, int qd)
{
  if (gw >= Mt) return;
  const int mi = gw;
  const int k0 = mi*16 + qd*4;
  const short* ap = Tok + (long)(mi*16 + ln)*SA;
  short8 af[KCH];
  #pragma unroll
  for (int kc = 0; kc < KCH; ++kc) af[kc] = *(const short8*)(ap + qd*8 + kc*32);
  #pragma unroll
  for (int ni = 0; ni < Nt; ++ni) {
    const int row = ni*16 + ln;
    const short* bp = Wv + (long)row*SB;
    f32x4 acc = {0.f,0.f,0.f,0.f};
    #pragma unroll
    for (int kc = 0; kc < KCH; ++kc)
      acc = __builtin_amdgcn_mfma_f32_16x16x32_bf16(
          af[kc], *(const short8*)(bp + qd*8 + kc*32), acc, 0,0,0);
    short4v pk;
    pk.x = sb(acc[0]); pk.y = sb(acc[1]); pk.z = sb(acc[2]); pk.w = sb(acc[3]);
    *(short4v*)(Z + row*SZ + (k0 ^ ((ln & 7) << 3))) = pk;
  }
}

// ---------------------------------------------------------------- per-head pieces
template<int A>
__device__ __forceinline__ void build_head(
    short* __restrict__ SMEM, const short* __restrict__ wsec,
    const float* __restrict__ bq, int h, int gw, int ln, int qd)
{
  constexpr int MQ  = A ? 5 : 7;
  constexpr int MKV = A ? 7 : 5;
  constexpr int MO  = A ? 7 : 5;
  constexpr int QCH = A ? 4 : 3;
  constexpr int KCH = A ? 3 : 4;
  constexpr int SWQ = A ? 128 : 96;   // wq global stride
  constexpr int SWK = A ? 96 : 128;   // wk global stride
  constexpr int SWV = A ? 96 : 128;   // wvt global stride
  constexpr int STQ = A ? 136 : 104;  // q-token LDS stride
  constexpr int STK = A ? 104 : 136;  // kv-token LDS stride
  const short* tokq = SMEM + (A ? TOKTP : TOKSP);
  const short* tokk = SMEM + (A ? TOKSP : TOKTP);
  short* Z1 = SMEM + (A ? G1Z1 : G0Z1);
  short* Z2 = SMEM + (A ? G1Z2 : G0Z2);
  short* Z3 = SMEM + (A ? G1Z3 : G0Z3);
  const short* wkT = wsec + (A ? W_TSWK : W_STWK);
  const short* wqT = wsec + (A ? W_TSWQ : W_STWQ);
  const short* wvt = wsec + (A ? W_VTS  : W_VST);
  const int base = h * HD;
  build_kq<MKV, KCH, SWK, STK>(wkT + (long)base*SWK, tokk, Z1, nullptr, gw, ln, qd);
  build_kq<MQ,  QCH, SWQ, STQ>(wqT + (long)base*SWQ, tokq, Z2, bq + base, gw, ln, qd);
  build_vt<MKV, MO, KCH, STK, SWV, 128>(tokk, wvt + (long)h*(MO*16*SWV), Z3, gw, ln, qd);
}

template<int A>
__device__ __forceinline__ void chain_head(
    const short* __restrict__ SMEM, f32x4* __restrict__ accO,
    int gw, int ln, int qd)
{
  constexpr int KVR = A ? 100 : 66;
  constexpr int MQ  = A ? 5 : 7;
  constexpr int MKV = A ? 7 : 5;
  constexpr int MO  = A ? 7 : 5;
  constexpr int PCH = A ? 4 : 3;
  if (gw >= MQ) return;
  const short* Z1 = SMEM + (A ? G1Z1 : G0Z1);
  const short* Z2 = SMEM + (A ? G1Z2 : G0Z2);
  const short* Z3 = SMEM + (A ? G1Z3 : G0Z3);
  const int msk = (ln & 7) << 3;

  // S^T = K @ Q^T : lane holds q=ln, kv = ni*16+qd*4+r
  const short* bqp = Z2 + (gw*16 + ln)*64;
  const short8 qf0 = *(const short8*)(bqp + ((qd*8     ) ^ msk));
  const short8 qf1 = *(const short8*)(bqp + ((qd*8 + 32) ^ msk));
  f32x4 s[MKV];
  #pragma unroll
  for (int ni = 0; ni < MKV; ++ni) {
    const short* ap = Z1 + (ni*16 + ln)*64;
    f32x4 acc = {0.f,0.f,0.f,0.f};
    acc = __builtin_amdgcn_mfma_f32_16x16x32_bf16(
        *(const short8*)(ap + ((qd*8     ) ^ msk)), qf0, acc, 0,0,0);
    acc = __builtin_amdgcn_mfma_f32_16x16x32_bf16(
        *(const short8*)(ap + ((qd*8 + 32) ^ msk)), qf1, acc, 0,0,0);
    s[ni] = acc;
  }
  // mask pad kv + scale
  #pragma unroll
  for (int ni = 0; ni < MKV; ++ni) {
    #pragma unroll
    for (int r = 0; r < 4; ++r) {
      const int kv = ni*16 + qd*4 + r;
      s[ni][r] = (kv < KVR) ? s[ni][r]*0.125f : -1e30f;
    }
  }
  // softmax over kv (own regs + shfl_xor 16, 32)
  float mx = -1e30f;
  #pragma unroll
  for (int ni = 0; ni < MKV; ++ni)
    #pragma unroll
    for (int r = 0; r < 4; ++r) mx = fmaxf(mx, s[ni][r]);
  mx = fmaxf(mx, __shfl_xor(mx, 16));
  mx = fmaxf(mx, __shfl_xor(mx, 32));
  float l = 0.f;
  #pragma unroll
  for (int ni = 0; ni < MKV; ++ni)
    #pragma unroll
    for (int r = 0; r < 4; ++r) {
      float p = __expf(s[ni][r] - mx);
      s[ni][r] = p; l += p;
    }
  l += __shfl_xor(l, 16);
  l += __shfl_xor(l, 32);
  const float rs = 1.f / l;
  // pack P rows (bf16 pairs); tiles beyond MKV are zero
  unsigned int plo[2*PCH], phi[2*PCH];
  #pragma unroll
  for (int ni = 0; ni < 2*PCH; ++ni) {
    if (ni < MKV) {
      plo[ni] = pk2(s[ni][0]*rs, s[ni][1]*rs);
      phi[ni] = pk2(s[ni][2]*rs, s[ni][3]*rs);
    } else { plo[ni] = 0u; phi[ni] = 0u; }
  }
  // PV per-kc: build ONE pf fragment, sweep all MO accumulators.
  #pragma unroll
  for (int kc = 0; kc < PCH; ++kc) {
    PF pf;
    #pragma unroll
    for (int w = 0; w < 4; ++w) {
      const int srcLane = ln + 16*((qd & 1)*2 + (w >> 1));
      int va, vb;
      if (w & 1) {
        va = __shfl((int)phi[2*kc  ], srcLane, 64);
        vb = __shfl((int)phi[2*kc+1], srcLane, 64);
      } else {
        va = __shfl((int)plo[2*kc  ], srcLane, 64);
        vb = __shfl((int)plo[2*kc+1], srcLane, 64);
      }
      pf.u[w] = (qd < 2) ? (unsigned int)va : (unsigned int)vb;
    }
    #pragma unroll
    for (int oi = 0; oi < MO; ++oi) {
      const short* ap = Z3 + (oi*16 + ln)*128;
      short8 af = *(const short8*)(ap + ((qd*8 + kc*32) ^ msk));
      accO[oi] = __builtin_amdgcn_mfma_f32_16x16x32_bf16(af, pf.s, accO[oi], 0,0,0);
    }
  }
}

// ---------------------------------------------------------------- k_attn2 (mega)
// 1024 threads: waves 0-7 flavor A=0, waves 8-15 A=1. r6/r9 structure
// (2 barriers/head, register accO) -- best measured chain. NEW vs r9:
// k_prep is FUSED into the prologue: x, M^T=(tadj*tmask)^T and A are staged
// into the (currently dead) zone region and the spT/tp tokens are computed
// directly into TOKSP/TOKTP -- eliminates the k_prep dispatch and its
// 84 MB global token round-trip.
__global__ __launch_bounds__(1024) void k_attn2(
    const float* __restrict__ x, const float* __restrict__ adj,
    const float* __restrict__ sadj, const float* __restrict__ tmask,
    const float* __restrict__ tadj,
    const bf16* __restrict__ wsec_,
    const float* __restrict__ st_bq, const float* __restrict__ ts_bq,
    const float* __restrict__ bias2,
    const float* __restrict__ alpha, const float* __restrict__ beta,
    const float* __restrict__ fcw, const float* __restrict__ fcb,
    float* __restrict__ out)
{
  __shared__ __align__(16) short SMEM[SMEM_SH];
  const int b = blockIdx.x, tid = threadIdx.x;
  const long bb = (long)b * (CC*TT);
  const int wave = tid >> 6, lane = tid & 63, ln = lane & 15, qd = lane >> 4;
  const int g = wave >> 3, gw = wave & 7;
  const short* wsec = (const short*)wsec_;

  // ---------------- fused prep prologue ----------------
  float* s_x  = (float*)(SMEM + P_SX);    // [66][100]
  float* s_Mt = (float*)(SMEM + P_SMT);   // [100][100] transposed mask*adj
  float* s_A  = (float*)(SMEM + P_SA);    // [22][22]
  float* s_dis= (float*)(SMEM + P_SDIS);  // [22]
  if (tid < JJ) {
    float dsum = 0.f;
    for (int i = 0; i < JJ; ++i) dsum += adj[tid*JJ + i];
    s_dis[tid] = dsum > 0.f ? rsqrtf(dsum) : 0.f;
  }
  for (int o = tid; o < CC*TT; o += 1024) s_x[o] = x[bb + o];
  for (int o = tid; o < TT*TT; o += 1024) {
    int f = o / TT, t = o - f*TT;
    s_Mt[t*TT + f] = tadj[o] * tmask[o];
  }
  __syncthreads();
  for (int o = tid; o < JJ*JJ; o += 1024) {
    int v = o / JJ, j = o - v*JJ;
    s_A[o] = sadj[o] * adj[o] * s_dis[v] * s_dis[j];
  }
  __syncthreads();
  // spT[t][c] -> TOKSP [112][104], 4-t blocks with float4 x reads
  for (int o = tid; o < 28*104; o += 1024) {
    int t4 = o / 104, c = o - t4*104;
    int t = t4*4;
    float ax=0.f, ay=0.f, az=0.f, aw=0.f;
    if (t < TT && c < CC) {
      int v = c/3, dd = c - v*3;
      for (int j = 0; j < JJ; ++j) {
        float av = s_A[v*JJ + j];
        float4 xv = *(const float4*)(s_x + (j*3+dd)*TT + t);
        ax += av*xv.x; ay += av*xv.y; az += av*xv.z; aw += av*xv.w;
      }
    }
    SMEM[TOKSP + (t  )*104 + c] = sb(ax);
    SMEM[TOKSP + (t+1)*104 + c] = sb(ay);
    SMEM[TOKSP + (t+2)*104 + c] = sb(az);
    SMEM[TOKSP + (t+3)*104 + c] = sb(aw);
  }
  // tp[n][f] -> TOKTP [80][136], 4-f blocks with float4 Mt reads
  for (int o = tid; o < 80*34; o += 1024) {
    int n = o / 34, f4 = o - n*34;
    int f = f4*4;
    float ax=0.f, ay=0.f, az=0.f, aw=0.f;
    if (n < CC && f < TT) {
      for (int t = 0; t < TT; ++t) {
        float xv = s_x[n*TT + t];
        float4 w = *(const float4*)(s_Mt + t*TT + f);
        ax += xv*w.x; ay += xv*w.y; az += xv*w.z; aw += xv*w.w;
      }
    }
    short4v pk;
    pk.x = sb(ax); pk.y = sb(ay); pk.z = sb(az); pk.w = sb(aw);
    *(short4v*)(SMEM + TOKTP + n*136 + f) = pk;
  }
  __syncthreads();   // tokens done; staging regions (zones) now reusable
  // Z3 pad kv-cols zero (builds never rewrite them; PV reads them as zeros)
  for (int o = tid; o < 80*16; o += 1024) {
    int r = o >> 4, kv = 80 + (o & 15);
    SMEM[G0Z3 + r*128 + (kv ^ ((r & 7) << 3))] = 0;
  }
  for (int o = tid; o < 112*16; o += 1024) {
    int r = o >> 4, kv = 112 + (o & 15);
    SMEM[G1Z3 + r*128 + (kv ^ ((r & 7) << 3))] = 0;
  }

  f32x4 accO[7];
  { f32x4 z = {0.f,0.f,0.f,0.f};
    #pragma unroll
    for (int i = 0; i < 7; ++i) accO[i] = z; }

  for (int h = 0; h < HH; ++h) {
    __syncthreads();   // pads/tokens done (h=0); zone WAR (h>0)
    if (g == 0) build_head<0>(SMEM, wsec, st_bq, h, gw, ln, qd);
    else        build_head<1>(SMEM, wsec, ts_bq, h, gw, ln, qd);
    __syncthreads();
    if (g == 0) chain_head<0>(SMEM, accO, gw, ln, qd);
    else        chain_head<1>(SMEM, accO, gw, ln, qd);
  }

  // ---------------- fused epilogue (zones dead) ----------------
  float* comb = (float*)(SMEM + G0Z1);   // [66][101] floats = 26,664 B
  float* s_w  = comb + 6668;             // fcw^T [t][f], 40,000 B
  __syncthreads();
  // E1: G0 dumps accO (=); G1 stages fcw^T
  if (g == 0) {
    if (gw < 7) {
      const int t = gw*16 + ln;
      if (t < TT) {
        #pragma unroll
        for (int oi = 0; oi < 5; ++oi)
          #pragma unroll
          for (int r = 0; r < 4; ++r) {
            const int c = oi*16 + qd*4 + r;
            if (c < CC) comb[c*CPAD + t] = accO[oi][r];
          }
      }
    }
  } else {
    for (int o = tid - 512; o < TT*TT; o += 512) {
      int f = o / TT, t = o - f*TT;
      s_w[t*TT + f] = fcw[o];
    }
  }
  __syncthreads();
  // E2: G1 dumps accO (+=)
  if (g == 1 && gw < 5) {
    const int c = gw*16 + ln;
    if (c < CC) {
      #pragma unroll
      for (int oi = 0; oi < 7; ++oi)
        #pragma unroll
        for (int r = 0; r < 4; ++r) {
          const int t = oi*16 + qd*4 + r;
          if (t < TT) comb[c*CPAD + t] += accO[oi][r];
        }
    }
  }
  __syncthreads();
  // E3: folded output biases
  for (int o = tid; o < CC*TT; o += 1024) {
    int c = o / TT, t = o - c*TT;
    comb[c*CPAD + t] += bias2[c] + bias2[128 + t];
  }
  __syncthreads();
  // E4: LN over channels (2 lanes per t) + residual
  if (tid < 2*TT) {
    const int t = tid >> 1, hf = tid & 1;
    float part = 0.f;
    for (int c = hf; c < CC; c += 2) part += comb[c*CPAD + t];
    float mean = (part + __shfl_xor(part, 1)) * (1.f/CC);
    float vp = 0.f;
    for (int c = hf; c < CC; c += 2) { float dv = comb[c*CPAD + t] - mean; vp += dv*dv; }
    float var = (vp + __shfl_xor(vp, 1)) * (1.f/CC);
    float rstd = 1.f / sqrtf(var + 1e-5f);
    for (int c = hf; c < CC; c += 2) {
      float y = (comb[c*CPAD + t] - mean) * rstd * alpha[c] + beta[c];
      comb[c*CPAD + t] = y + x[bb + c*TT + t];
    }
  }
  __syncthreads();
  // E5: FC over t (float4 weights) + tanh -> out
  for (int o = tid; o < CC*25; o += 1024) {
    int c = o / 25, f4 = o - c*25;
    int f = f4*4;
    const float* cr = comb + c*CPAD;
    float ax=0.f, ay=0.f, az=0.f, aw=0.f;
    for (int t = 0; t < TT; ++t) {
      float xv = cr[t];
      float4 wv = *(const float4*)(s_w + t*TT + f);
      ax += xv*wv.x; ay += xv*wv.y; az += xv*wv.z; aw += xv*wv.w;
    }
    float4 r4;
    r4.x = tanhf(ax + fcb[f  ]); r4.y = tanhf(ay + fcb[f+1]);
    r4.z = tanhf(az + fcb[f+2]); r4.w = tanhf(aw + fcb[f+3]);
    *(float4*)(out + bb + c*TT + f) = r4;
  }
}

// ---------------------------------------------------------------- R4 fallback
__global__ __launch_bounds__(128) void k_fused(
    const float* __restrict__ x, const float* __restrict__ adj,
    const float* __restrict__ sadj, const float* __restrict__ tmask,
    const float* __restrict__ tadj,
    const float* __restrict__ st_wq, const float* __restrict__ st_bq,
    const float* __restrict__ st_wk, const float* __restrict__ st_bk,
    const float* __restrict__ st_wv, const float* __restrict__ st_bv,
    const float* __restrict__ st_wo, const float* __restrict__ st_bo,
    const float* __restrict__ ts_wq, const float* __restrict__ ts_bq,
    const float* __restrict__ ts_wk, const float* __restrict__ ts_bk,
    const float* __restrict__ ts_wv, const float* __restrict__ ts_bv,
    const float* __restrict__ ts_wo, const float* __restrict__ ts_bo,
    const float* __restrict__ alpha, const float* __restrict__ beta,
    const float* __restrict__ fcw, const float* __restrict__ fcb,
    float* __restrict__ out)
{
  __shared__ float s_sp[CC*TT];
  __shared__ float s_tp[CC*TT];
  __shared__ __align__(16) float s_kv[2*TT*HD];
  __shared__ float s_comb[CC*CPAD];
  __shared__ float s_A[JJ*JJ];
  __shared__ float s_dis[JJ];

  const int b = blockIdx.x, tid = threadIdx.x;
  const long bb = (long)b * (CC*TT);
  float* s_xs = s_comb;
  float* s_Mt = s_kv;

  if (tid < JJ) {
    float dsum = 0.f;
    for (int i = 0; i < JJ; ++i) dsum += adj[tid*JJ + i];
    s_dis[tid] = dsum > 0.f ? rsqrtf(dsum) : 0.f;
  }
  for (int o = tid; o < CC*TT; o += 128) s_xs[o] = x[bb + o];
  for (int o = tid; o < TT*TT; o += 128) {
    int f = o / TT, t = o - f*TT;
    s_Mt[t*TT + f] = tadj[o] * tmask[o];
  }
  __syncthreads();
  for (int o = tid; o < JJ*JJ; o += 128) {
    int v = o / JJ, j = o - v*JJ;
    s_A[o] = sadj[o] * adj[o] * s_dis[v] * s_dis[j];
  }
  __syncthreads();

  for (int o = tid; o < CC*TT; o += 128) {
    int c = o / TT, t = o - c*TT, v = c / 3, dd = c - v*3;
    float acc = 0.f;
    for (int j = 0; j < JJ; ++j) acc += s_A[v*JJ + j] * s_xs[(j*3 + dd)*TT + t];
    s_sp[o] = acc;
  }
  for (int o = tid; o < CC*TT; o += 128) {
    int n = o / TT, f = o - n*TT;
    float a0 = 0.f, a1 = 0.f;
    for (int t = 0; t < TT; t += 2) {
      a0 += s_xs[n*TT + t    ] * s_Mt[(t    )*TT + f];
      a1 += s_xs[n*TT + t + 1] * s_Mt[(t + 1)*TT + f];
    }
    s_tp[o] = a0 + a1;
  }
  __syncthreads();

  for (int o = tid; o < CC*TT; o += 128) {
    int c = o / TT, t = o - c*TT;
    s_comb[c*CPAD + t] = st_bo[c] + ts_bo[t];
  }

  {
    float* s_k = s_kv;
    float* s_v = s_kv + TT*HD;
    for (int h = 0; h < HH; ++h) {
      const int base = h*HD;
      __syncthreads();
      {
        const int d = tid & 63, krow = tid >> 6;
        for (int kk = 0; kk < CC/2; ++kk) {
          int k = kk*2 + krow;
          float aK = st_bk[base + d], aV = st_bv[base + d];
          const float* tr = s_tp + k*TT;
          for (int t = 0; t < TT; ++t) {
            float a = tr[t];
            aK += a * st_wk[(long)t*EE + base + d];
            aV += a * st_wv[(long)t*EE + base + d];
          }
          s_k[k*HD + d] = aK;
          s_v[k*HD + d] = aV;
        }
      }
      __syncthreads();
      if (tid < TT) {
        const int q = tid;
        float qv[HD];
        #pragma unroll
        for (int d = 0; d < HD; ++d) qv[d] = st_bq[base + d];
        for (int c = 0; c < CC; ++c) {
          float a = s_sp[c*TT + q];
          const float* wr = st_wq + (long)c*EE + base;
          #pragma unroll
          for (int d = 0; d < HD; ++d) qv[d] += a * wr[d];
        }
        float m = -INFINITY, l = 0.f, ov[HD];
        #pragma unroll
        for (int d = 0; d < HD; ++d) ov[d] = 0.f;
        for (int k = 0; k < CC; ++k) {
          const float4* kr4 = (const float4*)(s_k + k*HD);
          float s0=0.f,s1=0.f,s2=0.f,s3=0.f;
          #pragma unroll
          for (int i = 0; i < 16; ++i) {
            float4 kk4 = kr4[i];
            s0 += qv[4*i  ]*kk4.x; s1 += qv[4*i+1]*kk4.y;
            s2 += qv[4*i+2]*kk4.z; s3 += qv[4*i+3]*kk4.w;
          }
          float s  = (s0+s1+s2+s3) * 0.125f;
          float mn = fmaxf(m, s);
          float corr = __expf(m - mn);
          float p    = __expf(s - mn);
          l = l*corr + p;
          const float4* vr4 = (const float4*)(s_v + k*HD);
          #pragma unroll
          for (int i = 0; i < 16; ++i) {
            float4 vv4 = vr4[i];
            ov[4*i  ] = ov[4*i  ]*corr + p*vv4.x;
            ov[4*i+1] = ov[4*i+1]*corr + p*vv4.y;
            ov[4*i+2] = ov[4*i+2]*corr + p*vv4.z;
            ov[4*i+3] = ov[4*i+3]*corr + p*vv4.w;
          }
          m = mn;
        }
        float rl = 1.f/l;
        #pragma unroll
        for (int d = 0; d < HD; ++d) ov[d] *= rl;
        for (int c = 0; c < CC; ++c) {
          const float* wr = st_wo + (long)base*CC + c;
          float a0=0.f,a1=0.f,a2=0.f,a3=0.f;
          #pragma unroll
          for (int d = 0; d < HD; d += 4) {
            a0 += ov[d  ]*wr[(long)(d  )*CC]; a1 += ov[d+1]*wr[(long)(d+1)*CC];
            a2 += ov[d+2]*wr[(long)(d+2)*CC]; a3 += ov[d+3]*wr[(long)(d+3)*CC];
          }
          s_comb[c*CPAD + q] += a0+a1+a2+a3;
        }
      }
    }
  }

  {
    float* s_k = s_kv;
    float* s_v = s_kv + TT*HD;
    for (int h = 0; h < HH; ++h) {
      const int base = h*HD;
      __syncthreads();
      {
        const int d = tid & 63, krow = tid >> 6;
        for (int kk = 0; kk < TT/2; ++kk) {
          int k = kk*2 + krow;
          float aK = ts_bk[base + d], aV = ts_bv[base + d];
          for (int c = 0; c < CC; ++c) {
            float a = s_sp[c*TT + k];
            aK += a * ts_wk[(long)c*EE + base + d];
            aV += a * ts_wv[(long)c*EE + base + d];
          }
          s_k[k*HD + d] = aK;
          s_v[k*HD + d] = aV;
        }
      }
      __syncthreads();
      if (tid < CC) {
        const int q = tid;
        float qv[HD];
        #pragma unroll
        for (int d = 0; d < HD; ++d) qv[d] = ts_bq[base + d];
        const float* tr = s_tp + q*TT;
        for (int t = 0; t < TT; ++t) {
          float a = tr[t];
          const float* wr = ts_wq + (long)t*EE + base;
          #pragma unroll
          for (int d = 0; d < HD; ++d) qv[d] += a * wr[d];
        }
        float m = -INFINITY, l = 0.f, ov[HD];
        #pragma unroll
        for (int d = 0; d < HD; ++d) ov[d] = 0.f;
        for (int k = 0; k < TT; ++k) {
          const float4* kr4 = (const float4*)(s_k + k*HD);
          float s0=0.f,s1=0.f,s2=0.f,s3=0.f;
          #pragma unroll
          for (int i = 0; i < 16; ++i) {
            float4 kk4 = kr4[i];
            s0 += qv[4*i  ]*kk4.x; s1 += qv[4*i+1]*kk4.y;
            s2 += qv[4*i+2]*kk4.z; s3 += qv[4*i+3]*kk4.w;
          }
          float s  = (s0+s1+s2+s3) * 0.125f;
          float mn = fmaxf(m, s);
          float corr = __expf(m - mn);
          float p    = __expf(s - mn);
          l = l*corr + p;
          const float4* vr4 = (const float4*)(s_v + k*HD);
          #pragma unroll
          for (int i = 0; i < 16; ++i) {
            float4 vv4 = vr4[i];
            ov[4*i  ] = ov[4*i  ]*corr + p*vv4.x;
            ov[4*i+1] = ov[4*i+1]*corr + p*vv4.y;
            ov[4*i+2] = ov[4*i+2]*corr + p*vv4.z;
            ov[4*i+3] = ov[4*i+3]*corr + p*vv4.w;
          }
          m = mn;
        }
        float rl = 1.f/l;
        #pragma unroll
        for (int d = 0; d < HD; ++d) ov[d] *= rl;
        for (int t = 0; t < TT; ++t) {
          const float* wr = ts_wo + (long)base*TT + t;
          float a0=0.f,a1=0.f,a2=0.f,a3=0.f;
          #pragma unroll
          for (int d = 0; d < HD; d += 4) {
            a0 += ov[d  ]*wr[(long)(d  )*TT]; a1 += ov[d+1]*wr[(long)(d+1)*TT];
            a2 += ov[d+2]*wr[(long)(d+2)*TT]; a3 += ov[d+3]*wr[(long)(d+3)*TT];
          }
          s_comb[q*CPAD + t] += a0+a1+a2+a3;
        }
      }
    }
  }
  __syncthreads();

  if (tid < TT) {
    const int t = tid;
    float mean = 0.f;
    for (int c = 0; c < CC; ++c) mean += s_comb[c*CPAD + t];
    mean *= (1.f/CC);
    float var = 0.f;
    for (int c = 0; c < CC; ++c) { float dv = s_comb[c*CPAD + t] - mean; var += dv*dv; }
    var *= (1.f/CC);
    float rstd = 1.f / sqrtf(var + 1e-5f);
    for (int c = 0; c < CC; ++c) {
      float y = (s_comb[c*CPAD + t] - mean) * rstd * alpha[c] + beta[c];
      s_comb[c*CPAD + t] = y + x[bb + c*TT + t];
    }
  }
  __syncthreads();

  float* s_w = s_kv;
  for (int o = tid; o < TT*TT; o += 128) {
    int f = o / TT, t = o - f*TT;
    s_w[t*TT + f] = fcw[o];
  }
  __syncthreads();

  for (int o = tid; o < CC*TT; o += 128) {
    int c = o / TT, f = o - c*TT;
    const float* cr = s_comb + c*CPAD;
    float a0 = 0.f, a1 = 0.f;
    for (int t = 0; t < TT; t += 2) {
      a0 += cr[t    ] * s_w[(t    )*TT + f];
      a1 += cr[t + 1] * s_w[(t + 1)*TT + f];
    }
    out[bb + o] = tanhf(a0 + a1 + fcb[f]);
  }
}

// ---------------------------------------------------------------- launch
extern "C" void kernel_launch(void* const* d_in, const int* in_sizes, int n_in,
                              void* d_out, int out_size, void* d_ws, size_t ws_size,
                              hipStream_t stream) {
  const float* x     = (const float*)d_in[0];
  const float* adj   = (const float*)d_in[1];
  const float* sadj  = (const float*)d_in[2];
  const float* tmask = (const float*)d_in[3];
  const float* tadj  = (const float*)d_in[4];
  const float* st_wq = (const float*)d_in[5];  const float* st_bq = (const float*)d_in[6];
  const float* st_wk = (const float*)d_in[7];  const float* st_bk = (const float*)d_in[8];
  const float* st_wv = (const float*)d_in[9];  const float* st_bv = (const float*)d_in[10];
  const float* st_wo = (const float*)d_in[11]; const float* st_bo = (const float*)d_in[12];
  const float* ts_wq = (const float*)d_in[13]; const float* ts_bq = (const float*)d_in[14];
  const float* ts_wk = (const float*)d_in[15]; const float* ts_bk = (const float*)d_in[16];
  const float* ts_wv = (const float*)d_in[17]; const float* ts_bv = (const float*)d_in[18];
  const float* ts_wo = (const float*)d_in[19]; const float* ts_bo = (const float*)d_in[20];
  const float* alpha = (const float*)d_in[21]; const float* beta  = (const float*)d_in[22];
  const float* fcw   = (const float*)d_in[23]; const float* fcb   = (const float*)d_in[24];
  float* out = (float*)d_out;

  const int B = in_sizes[0] / (CC*TT);
  const size_t need = (size_t)W_TOTAL * 2 + 1024;   // weights + bias2

  if (ws_size >= need) {
    bf16*  wsec  = (bf16*)d_ws;
    float* bias2 = (float*)((char*)d_ws + (size_t)W_TOTAL*2);

    k_wprep<<<1553, 256, 0, stream>>>(st_wk, st_wq, ts_wk, ts_wq,
                                      st_wv, st_wo, ts_wv, ts_wo,
                                      st_bo, st_bv, ts_bo, ts_bv,
                                      wsec, bias2);
    k_attn2<<<B, 1024, 0, stream>>>(x, adj, sadj, tmask, tadj, wsec,
                                    st_bq, ts_bq, bias2,
                                    alpha, beta, fcw, fcb, out);
  } else {
    k_fused<<<B, 128, 0, stream>>>(x, adj, sadj, tmask, tadj,
                                   st_wq, st_bq, st_wk, st_bk, st_wv, st_bv, st_wo, st_bo,
                                   ts_wq, ts_bq, ts_wk, ts_bk, ts_wv, ts_bv, ts_wo, ts_bo,
                                   alpha, beta, fcw, fcb, out);
  }
}

// Round 14
// 667.719 us; speedup vs baseline: 1.7737x; 1.0215x over previous
//
#include <hip/hip_runtime.h>
#include <hip/hip_bf16.h>
#include <math.h>
#include <stdint.h>

typedef __hip_bfloat16 bf16;
typedef __attribute__((ext_vector_type(8))) short short8;
typedef __attribute__((ext_vector_type(4))) short short4v;
typedef __attribute__((ext_vector_type(4))) float f32x4;
typedef __attribute__((ext_vector_type(4))) unsigned int uint4v;
union PF { uint4v u; short8 s; };

#define CC 66      // channels = J*DIMS
#define TT 100     // time steps
#define JJ 22      // joints
#define HH 8       // heads
#define HD 64      // head dim
#define EE 512     // embed
#define CPAD 101   // comb stride (floats)

// global token layouts in ws (zero-padded)
#define SPT_R 112  // spT rows
#define SPT_S 96   // spT stride
#define TP_R 80    // tp rows
#define TP_S 128   // tp stride

// weight section offsets (bf16 elements) inside ws
#define W_STWK 0                    // [512][128]
#define W_STWQ 65536                // [512][96]
#define W_TSWK 114688               // [512][96]
#define W_TSWQ 163840               // [512][128]
#define W_VST  229376               // WtildeT st: [8][80][128]
#define W_VTS  311296               // WtildeT ts: [8][112][96]
#define W_TOTAL 397312

// k_attn2 LDS layout (short offsets)
#define TOKSP 0        // [112][104]
#define TOKTP 11648    // [80][136]
#define G0Z1  22528    // K  A0 [80][64]
#define G0Z2  27648    // Q  A0 [112][64]
#define G0Z3  34816    // VT A0 [80][128]
#define G1Z1  45056    // K  A1 [112][64]
#define G1Z2  52224    // Q  A1 [80][64]
#define G1Z3  57344    // VT A1 [112][128]
#define SMEM_SH 71680  // 143,360 B

#define NWPB 1553      // weight-prep blocks at the front of k_pre's grid

__device__ __forceinline__ bf16 f2b(float v){ return __float2bfloat16(v); }
__device__ __forceinline__ short sb(float v){ __hip_bfloat16 h = __float2bfloat16(v); return *(short*)&h; }
__device__ __forceinline__ unsigned int pk2(float a, float b){
  unsigned short ua = (unsigned short)sb(a), ub = (unsigned short)sb(b);
  return (unsigned int)ua | ((unsigned int)ub << 16);
}

// ---------------------------------------------------------------- prep bodies
__device__ __forceinline__ void tr_body(
    const float* __restrict__ src, bf16* __restrict__ dst,
    int Rsrc, int Csrc, int JP, int IP, int blk, int tid)
{
  int o = blk*256 + tid;
  if (o >= JP*IP) return;
  int j = o / IP, i = o - j*IP;
  float v = (j < Csrc && i < Rsrc) ? src[(long)i*Csrc + j] : 0.f;
  dst[o] = f2b(v);
}

__device__ __forceinline__ void wt_body(
    const float* __restrict__ wv, const float* __restrict__ wo,
    bf16* __restrict__ dst, int OUT, int KDIM, int OP, int KP, int blk, int tid)
{
  int idx = blk*256 + tid;
  if (idx >= 8*OP*KP) return;
  int o = idx % OP;
  int hk = idx / OP;
  int k = hk % KP, h = hk / KP;
  float acc = 0.f;
  if (o < OUT && k < KDIM) {
    const float* wvp = wv + (long)k*EE + h*64;
    const float* wop = wo + (long)(h*64)*OUT + o;
    #pragma unroll 8
    for (int d = 0; d < 64; ++d) acc += wvp[d] * wop[(long)d*OUT];
  }
  dst[(long)h*OP*KP + (long)o*KP + k] = f2b(acc);
}

// ---------------------------------------------------------------- k_pre
// Merged weight-prep (blocks 0..1552; independent of token prep) and
// per-batch token prep (blocks 1553..1553+B-1). The two halves have no data
// dependence, so merging removes one launch gap and overlaps the weight-prep
// tail with the token-prep bulk.
__global__ __launch_bounds__(256) void k_pre(
    const float* __restrict__ x, const float* __restrict__ adj,
    const float* __restrict__ sadj, const float* __restrict__ tmask,
    const float* __restrict__ tadj,
    const float* __restrict__ st_wk, const float* __restrict__ st_wq,
    const float* __restrict__ ts_wk, const float* __restrict__ ts_wq,
    const float* __restrict__ st_wv, const float* __restrict__ st_wo,
    const float* __restrict__ ts_wv, const float* __restrict__ ts_wo,
    const float* __restrict__ st_bo, const float* __restrict__ st_bv,
    const float* __restrict__ ts_bo, const float* __restrict__ ts_bv,
    bf16* __restrict__ wsec, float* __restrict__ bias2,
    bf16* __restrict__ spT_all, bf16* __restrict__ tp_all)
{
  __shared__ float s_x[CC*TT];
  __shared__ float s_Mt[TT*TT];
  __shared__ float s_A[JJ*JJ];
  __shared__ float s_dis[JJ];
  const int blk = blockIdx.x, tid = threadIdx.x;

  if (blk < NWPB) {
    // ---------------- weight prep ----------------
    if      (blk <  256) tr_body(st_wk, wsec + W_STWK, TT, EE, EE, 128, blk,      tid);
    else if (blk <  448) tr_body(st_wq, wsec + W_STWQ, CC, EE, EE,  96, blk-256,  tid);
    else if (blk <  640) tr_body(ts_wk, wsec + W_TSWK, CC, EE, EE,  96, blk-448,  tid);
    else if (blk <  896) tr_body(ts_wq, wsec + W_TSWQ, TT, EE, EE, 128, blk-640,  tid);
    else if (blk < 1216) wt_body(st_wv, st_wo, wsec + W_VST, CC, TT,  80, 128, blk-896,  tid);
    else if (blk < 1552) wt_body(ts_wv, ts_wo, wsec + W_VTS, TT, CC, 112,  96, blk-1216, tid);
    else {
      if (tid < 128) {
        int c = tid; float a = 0.f;
        if (c < CC) {
          a = st_bo[c];
          for (int e = 0; e < EE; ++e) a += st_bv[e] * st_wo[(long)e*CC + c];
        }
        bias2[tid] = a;
      } else {
        int t = tid - 128; float a = 0.f;
        if (t < TT) {
          a = ts_bo[t];
          for (int e = 0; e < EE; ++e) a += ts_bv[e] * ts_wo[(long)e*TT + t];
        }
        bias2[tid] = a;
      }
    }
    return;
  }

  // ---------------- token prep (one block per batch) ----------------
  const int b = blk - NWPB;
  const long bb = (long)b * (CC*TT);

  if (tid < JJ) {
    float dsum = 0.f;
    for (int i = 0; i < JJ; ++i) dsum += adj[tid*JJ + i];
    s_dis[tid] = dsum > 0.f ? rsqrtf(dsum) : 0.f;
  }
  for (int o = tid; o < CC*TT; o += 256) s_x[o] = x[bb + o];
  for (int o = tid; o < TT*TT; o += 256) {
    int f = o / TT, t = o - f*TT;
    s_Mt[t*TT + f] = tadj[o] * tmask[o];
  }
  __syncthreads();
  for (int o = tid; o < JJ*JJ; o += 256) {
    int v = o / JJ, j = o - v*JJ;
    s_A[o] = sadj[o] * adj[o] * s_dis[v] * s_dis[j];
  }
  __syncthreads();

  bf16* spT = spT_all + (long)b * (SPT_R*SPT_S);
  bf16* tp  = tp_all  + (long)b * (TP_R*TP_S);

  // spT[t][c], 4-t blocks with float4 x reads
  for (int o = tid; o < 28*SPT_S; o += 256) {
    int t4 = o / SPT_S, c = o - t4*SPT_S;
    int t = t4*4;
    float ax=0.f, ay=0.f, az=0.f, aw=0.f;
    if (t < TT && c < CC) {
      int v = c/3, dd = c - v*3;
      for (int j = 0; j < JJ; ++j) {
        float av = s_A[v*JJ + j];
        float4 xv = *(const float4*)(s_x + (j*3+dd)*TT + t);
        ax += av*xv.x; ay += av*xv.y; az += av*xv.z; aw += av*xv.w;
      }
    }
    spT[(t  )*SPT_S + c] = f2b(ax);
    spT[(t+1)*SPT_S + c] = f2b(ay);
    spT[(t+2)*SPT_S + c] = f2b(az);
    spT[(t+3)*SPT_S + c] = f2b(aw);
  }
  // tp[n][f], 4-f blocks with float4 Mt reads
  for (int o = tid; o < TP_R*32; o += 256) {
    int n = o >> 5, f4 = o & 31;
    int f = f4*4;
    float ax=0.f, ay=0.f, az=0.f, aw=0.f;
    if (n < CC && f < TT) {
      for (int t = 0; t < TT; ++t) {
        float xv = s_x[n*TT + t];
        float4 w = *(const float4*)(s_Mt + t*TT + f);
        ax += xv*w.x; ay += xv*w.y; az += xv*w.z; aw += xv*w.w;
      }
    }
    short4v pk;
    pk.x = sb(ax); pk.y = sb(ay); pk.z = sb(az); pk.w = sb(aw);
    *(short4v*)(tp + n*TP_S + f) = pk;
  }
}

// ---------------------------------------------------------------- builds
// K/Q: m = d (4 tiles, 2 waves each); A-frags (global weights) reg-cached.
template<int Nt, int KCH, int SA, int SB>
__device__ __forceinline__ void build_kq(
    const short* __restrict__ W, const short* __restrict__ Tok,
    short* __restrict__ Z, const float* __restrict__ rowbias,
    int gw, int ln, int qd)
{
  const int mi = gw & 3;
  const int d0 = mi*16 + qd*4;
  const short* ap = W + (long)(mi*16 + ln)*SA;
  short8 af[KCH];
  #pragma unroll
  for (int kc = 0; kc < KCH; ++kc) af[kc] = *(const short8*)(ap + qd*8 + kc*32);
  float rb0=0.f, rb1=0.f, rb2=0.f, rb3=0.f;
  if (rowbias) { rb0=rowbias[d0]; rb1=rowbias[d0+1]; rb2=rowbias[d0+2]; rb3=rowbias[d0+3]; }
  constexpr int NU = (Nt + 1) / 2;
  #pragma unroll
  for (int u = 0; u < NU; ++u) {
    const int ni = (gw >> 2) + 2*u;
    if (ni < Nt) {
      const int row = ni*16 + ln;
      const short* bp = Tok + (long)row*SB;
      f32x4 acc = {0.f,0.f,0.f,0.f};
      #pragma unroll
      for (int kc = 0; kc < KCH; ++kc)
        acc = __builtin_amdgcn_mfma_f32_16x16x32_bf16(
            af[kc], *(const short8*)(bp + qd*8 + kc*32), acc, 0,0,0);
      short4v pk;
      pk.x = sb(acc[0]+rb0); pk.y = sb(acc[1]+rb1);
      pk.z = sb(acc[2]+rb2); pk.w = sb(acc[3]+rb3);
      *(short4v*)(Z + row*64 + (d0 ^ ((ln & 7) << 3))) = pk;
    }
  }
}

// VT: wave gw owns kv m-tile gw; A-frags (LDS tokens) reg-cached.
template<int Mt, int Nt, int KCH, int SA, int SB, int SZ>
__device__ __forceinline__ void build_vt(
    const short* __restrict__ Tok, const short* __restrict__ Wv,
    short* __restrict__ Z, int gw, int ln, int qd)
{
  if (gw >= Mt) return;
  const int mi = gw;
  const int k0 = mi*16 + qd*4;
  const short* ap = Tok + (long)(mi*16 + ln)*SA;
  short8 af[KCH];
  #pragma unroll
  for (int kc = 0; kc < KCH; ++kc) af[kc] = *(const short8*)(ap + qd*8 + kc*32);
  #pragma unroll
  for (int ni = 0; ni < Nt; ++ni) {
    const int row = ni*16 + ln;
    const short* bp = Wv + (long)row*SB;
    f32x4 acc = {0.f,0.f,0.f,0.f};
    #pragma unroll
    for (int kc = 0; kc < KCH; ++kc)
      acc = __builtin_amdgcn_mfma_f32_16x16x32_bf16(
          af[kc], *(const short8*)(bp + qd*8 + kc*32), acc, 0,0,0);
    short4v pk;
    pk.x = sb(acc[0]); pk.y = sb(acc[1]); pk.z = sb(acc[2]); pk.w = sb(acc[3]);
    *(short4v*)(Z + row*SZ + (k0 ^ ((ln & 7) << 3))) = pk;
  }
}

// ---------------------------------------------------------------- per-head pieces
template<int A>
__device__ __forceinline__ void build_head(
    short* __restrict__ SMEM, const short* __restrict__ wsec,
    const float* __restrict__ bq, int h, int gw, int ln, int qd)
{
  constexpr int MQ  = A ? 5 : 7;
  constexpr int MKV = A ? 7 : 5;
  constexpr int MO  = A ? 7 : 5;
  constexpr int QCH = A ? 4 : 3;
  constexpr int KCH = A ? 3 : 4;
  constexpr int SWQ = A ? 128 : 96;   // wq global stride
  constexpr int SWK = A ? 96 : 128;   // wk global stride
  constexpr int SWV = A ? 96 : 128;   // wvt global stride
  constexpr int STQ = A ? 136 : 104;  // q-token LDS stride
  constexpr int STK = A ? 104 : 136;  // kv-token LDS stride
  const short* tokq = SMEM + (A ? TOKTP : TOKSP);
  const short* tokk = SMEM + (A ? TOKSP : TOKTP);
  short* Z1 = SMEM + (A ? G1Z1 : G0Z1);
  short* Z2 = SMEM + (A ? G1Z2 : G0Z2);
  short* Z3 = SMEM + (A ? G1Z3 : G0Z3);
  const short* wkT = wsec + (A ? W_TSWK : W_STWK);
  const short* wqT = wsec + (A ? W_TSWQ : W_STWQ);
  const short* wvt = wsec + (A ? W_VTS  : W_VST);
  const int base = h * HD;
  build_kq<MKV, KCH, SWK, STK>(wkT + (long)base*SWK, tokk, Z1, nullptr, gw, ln, qd);
  build_kq<MQ,  QCH, SWQ, STQ>(wqT + (long)base*SWQ, tokq, Z2, bq + base, gw, ln, qd);
  build_vt<MKV, MO, KCH, STK, SWV, 128>(tokk, wvt + (long)h*(MO*16*SWV), Z3, gw, ln, qd);
}

template<int A>
__device__ __forceinline__ void chain_head(
    const short* __restrict__ SMEM, f32x4* __restrict__ accO,
    int gw, int ln, int qd)
{
  constexpr int KVR = A ? 100 : 66;
  constexpr int MQ  = A ? 5 : 7;
  constexpr int MKV = A ? 7 : 5;
  constexpr int MO  = A ? 7 : 5;
  constexpr int PCH = A ? 4 : 3;
  if (gw >= MQ) return;
  const short* Z1 = SMEM + (A ? G1Z1 : G0Z1);
  const short* Z2 = SMEM + (A ? G1Z2 : G0Z2);
  const short* Z3 = SMEM + (A ? G1Z3 : G0Z3);
  const int msk = (ln & 7) << 3;

  // S^T = K @ Q^T : lane holds q=ln, kv = ni*16+qd*4+r
  const short* bqp = Z2 + (gw*16 + ln)*64;
  const short8 qf0 = *(const short8*)(bqp + ((qd*8     ) ^ msk));
  const short8 qf1 = *(const short8*)(bqp + ((qd*8 + 32) ^ msk));
  f32x4 s[MKV];
  #pragma unroll
  for (int ni = 0; ni < MKV; ++ni) {
    const short* ap = Z1 + (ni*16 + ln)*64;
    f32x4 acc = {0.f,0.f,0.f,0.f};
    acc = __builtin_amdgcn_mfma_f32_16x16x32_bf16(
        *(const short8*)(ap + ((qd*8     ) ^ msk)), qf0, acc, 0,0,0);
    acc = __builtin_amdgcn_mfma_f32_16x16x32_bf16(
        *(const short8*)(ap + ((qd*8 + 32) ^ msk)), qf1, acc, 0,0,0);
    s[ni] = acc;
  }
  // mask pad kv + scale
  #pragma unroll
  for (int ni = 0; ni < MKV; ++ni) {
    #pragma unroll
    for (int r = 0; r < 4; ++r) {
      const int kv = ni*16 + qd*4 + r;
      s[ni][r] = (kv < KVR) ? s[ni][r]*0.125f : -1e30f;
    }
  }
  // softmax over kv (own regs + shfl_xor 16, 32)
  float mx = -1e30f;
  #pragma unroll
  for (int ni = 0; ni < MKV; ++ni)
    #pragma unroll
    for (int r = 0; r < 4; ++r) mx = fmaxf(mx, s[ni][r]);
  mx = fmaxf(mx, __shfl_xor(mx, 16));
  mx = fmaxf(mx, __shfl_xor(mx, 32));
  float l = 0.f;
  #pragma unroll
  for (int ni = 0; ni < MKV; ++ni)
    #pragma unroll
    for (int r = 0; r < 4; ++r) {
      float p = __expf(s[ni][r] - mx);
      s[ni][r] = p; l += p;
    }
  l += __shfl_xor(l, 16);
  l += __shfl_xor(l, 32);
  const float rs = 1.f / l;
  // pack P rows (bf16 pairs); tiles beyond MKV are zero
  unsigned int plo[2*PCH], phi[2*PCH];
  #pragma unroll
  for (int ni = 0; ni < 2*PCH; ++ni) {
    if (ni < MKV) {
      plo[ni] = pk2(s[ni][0]*rs, s[ni][1]*rs);
      phi[ni] = pk2(s[ni][2]*rs, s[ni][3]*rs);
    } else { plo[ni] = 0u; phi[ni] = 0u; }
  }
  // PV per-kc: build ONE pf fragment, sweep all MO accumulators.
  #pragma unroll
  for (int kc = 0; kc < PCH; ++kc) {
    PF pf;
    #pragma unroll
    for (int w = 0; w < 4; ++w) {
      const int srcLane = ln + 16*((qd & 1)*2 + (w >> 1));
      int va, vb;
      if (w & 1) {
        va = __shfl((int)phi[2*kc  ], srcLane, 64);
        vb = __shfl((int)phi[2*kc+1], srcLane, 64);
      } else {
        va = __shfl((int)plo[2*kc  ], srcLane, 64);
        vb = __shfl((int)plo[2*kc+1], srcLane, 64);
      }
      pf.u[w] = (qd < 2) ? (unsigned int)va : (unsigned int)vb;
    }
    #pragma unroll
    for (int oi = 0; oi < MO; ++oi) {
      const short* ap = Z3 + (oi*16 + ln)*128;
      short8 af = *(const short8*)(ap + ((qd*8 + kc*32) ^ msk));
      accO[oi] = __builtin_amdgcn_mfma_f32_16x16x32_bf16(af, pf.s, accO[oi], 0,0,0);
    }
  }
}

// ---------------------------------------------------------------- k_attn2 (mega)
// r9-exact structure (best measured): 1024 threads, waves 0-7 A=0 / 8-15 A=1,
// tokens staged once from global, 2 barriers/head, register accO, fused
// epilogue. The 64-VGPR cap's accO spill (~114 MB) is latency-hidden; three
// attempts to remove it (r9 attrs, r11 restructure, r12 hybrid) all lost more
// than it costs.
__global__ __launch_bounds__(1024) void k_attn2(
    const bf16* __restrict__ spT_all, const bf16* __restrict__ tp_all,
    const bf16* __restrict__ wsec_,
    const float* __restrict__ st_bq, const float* __restrict__ ts_bq,
    const float* __restrict__ bias2, const float* __restrict__ x,
    const float* __restrict__ alpha, const float* __restrict__ beta,
    const float* __restrict__ fcw, const float* __restrict__ fcb,
    float* __restrict__ out)
{
  __shared__ __align__(16) short SMEM[SMEM_SH];
  const int b = blockIdx.x, tid = threadIdx.x;
  const long bb = (long)b * (CC*TT);
  const int wave = tid >> 6, lane = tid & 63, ln = lane & 15, qd = lane >> 4;
  const int g = wave >> 3, gw = wave & 7;
  const short* wsec = (const short*)wsec_;

  // stage tokens -> LDS (padded strides 104/136 for bank spread)
  {
    const short* gsp = (const short*)(spT_all + (long)b*SPT_R*SPT_S);
    const short* gtp = (const short*)(tp_all  + (long)b*TP_R*TP_S);
    for (int o = tid; o < 112*12; o += 1024) {
      int r = o / 12, c8 = o - r*12;
      *(short8*)(SMEM + TOKSP + r*104 + c8*8) = *(const short8*)(gsp + r*SPT_S + c8*8);
    }
    for (int o = tid; o < 80*16; o += 1024) {
      int r = o >> 4, c8 = o & 15;
      *(short8*)(SMEM + TOKTP + r*136 + c8*8) = *(const short8*)(gtp + r*TP_S + c8*8);
    }
  }
  // Z3 pad kv-cols zero (builds never rewrite them; PV reads them as zeros)
  for (int o = tid; o < 80*16; o += 1024) {
    int r = o >> 4, kv = 80 + (o & 15);
    SMEM[G0Z3 + r*128 + (kv ^ ((r & 7) << 3))] = 0;
  }
  for (int o = tid; o < 112*16; o += 1024) {
    int r = o >> 4, kv = 112 + (o & 15);
    SMEM[G1Z3 + r*128 + (kv ^ ((r & 7) << 3))] = 0;
  }

  f32x4 accO[7];
  { f32x4 z = {0.f,0.f,0.f,0.f};
    #pragma unroll
    for (int i = 0; i < 7; ++i) accO[i] = z; }

  for (int h = 0; h < HH; ++h) {
    __syncthreads();   // staging/pads done (h=0); zone WAR (h>0)
    if (g == 0) build_head<0>(SMEM, wsec, st_bq, h, gw, ln, qd);
    else        build_head<1>(SMEM, wsec, ts_bq, h, gw, ln, qd);
    __syncthreads();
    if (g == 0) chain_head<0>(SMEM, accO, gw, ln, qd);
    else        chain_head<1>(SMEM, accO, gw, ln, qd);
  }

  // ---------------- fused epilogue (zones dead) ----------------
  float* comb = (float*)(SMEM + G0Z1);   // [66][101] floats = 26,664 B
  float* s_w  = comb + 6668;             // fcw^T [t][f], 40,000 B
  __syncthreads();
  // E1: G0 dumps accO (=); G1 stages fcw^T
  if (g == 0) {
    if (gw < 7) {
      const int t = gw*16 + ln;
      if (t < TT) {
        #pragma unroll
        for (int oi = 0; oi < 5; ++oi)
          #pragma unroll
          for (int r = 0; r < 4; ++r) {
            const int c = oi*16 + qd*4 + r;
            if (c < CC) comb[c*CPAD + t] = accO[oi][r];
          }
      }
    }
  } else {
    for (int o = tid - 512; o < TT*TT; o += 512) {
      int f = o / TT, t = o - f*TT;
      s_w[t*TT + f] = fcw[o];
    }
  }
  __syncthreads();
  // E2: G1 dumps accO (+=)
  if (g == 1 && gw < 5) {
    const int c = gw*16 + ln;
    if (c < CC) {
      #pragma unroll
      for (int oi = 0; oi < 7; ++oi)
        #pragma unroll
        for (int r = 0; r < 4; ++r) {
          const int t = oi*16 + qd*4 + r;
          if (t < TT) comb[c*CPAD + t] += accO[oi][r];
        }
    }
  }
  __syncthreads();
  // E3: folded output biases
  for (int o = tid; o < CC*TT; o += 1024) {
    int c = o / TT, t = o - c*TT;
    comb[c*CPAD + t] += bias2[c] + bias2[128 + t];
  }
  __syncthreads();
  // E4: LN over channels (2 lanes per t) + residual
  if (tid < 2*TT) {
    const int t = tid >> 1, hf = tid & 1;
    float part = 0.f;
    for (int c = hf; c < CC; c += 2) part += comb[c*CPAD + t];
    float mean = (part + __shfl_xor(part, 1)) * (1.f/CC);
    float vp = 0.f;
    for (int c = hf; c < CC; c += 2) { float dv = comb[c*CPAD + t] - mean; vp += dv*dv; }
    float var = (vp + __shfl_xor(vp, 1)) * (1.f/CC);
    float rstd = 1.f / sqrtf(var + 1e-5f);
    for (int c = hf; c < CC; c += 2) {
      float y = (comb[c*CPAD + t] - mean) * rstd * alpha[c] + beta[c];
      comb[c*CPAD + t] = y + x[bb + c*TT + t];
    }
  }
  __syncthreads();
  // E5: FC over t (float4 weights) + tanh -> out
  for (int o = tid; o < CC*25; o += 1024) {
    int c = o / 25, f4 = o - c*25;
    int f = f4*4;
    const float* cr = comb + c*CPAD;
    float ax=0.f, ay=0.f, az=0.f, aw=0.f;
    for (int t = 0; t < TT; ++t) {
      float xv = cr[t];
      float4 wv = *(const float4*)(s_w + t*TT + f);
      ax += xv*wv.x; ay += xv*wv.y; az += xv*wv.z; aw += xv*wv.w;
    }
    float4 r4;
    r4.x = tanhf(ax + fcb[f  ]); r4.y = tanhf(ay + fcb[f+1]);
    r4.z = tanhf(az + fcb[f+2]); r4.w = tanhf(aw + fcb[f+3]);
    *(float4*)(out + bb + c*TT + f) = r4;
  }
}

// ---------------------------------------------------------------- R4 fallback
__global__ __launch_bounds__(128) void k_fused(
    const float* __restrict__ x, const float* __restrict__ adj,
    const float* __restrict__ sadj, const float* __restrict__ tmask,
    const float* __restrict__ tadj,
    const float* __restrict__ st_wq, const float* __restrict__ st_bq,
    const float* __restrict__ st_wk, const float* __restrict__ st_bk,
    const float* __restrict__ st_wv, const float* __restrict__ st_bv,
    const float* __restrict__ st_wo, const float* __restrict__ st_bo,
    const float* __restrict__ ts_wq, const float* __restrict__ ts_bq,
    const float* __restrict__ ts_wk, const float* __restrict__ ts_bk,
    const float* __restrict__ ts_wv, const float* __restrict__ ts_bv,
    const float* __restrict__ ts_wo, const float* __restrict__ ts_bo,
    const float* __restrict__ alpha, const float* __restrict__ beta,
    const float* __restrict__ fcw, const float* __restrict__ fcb,
    float* __restrict__ out)
{
  __shared__ float s_sp[CC*TT];
  __shared__ float s_tp[CC*TT];
  __shared__ __align__(16) float s_kv[2*TT*HD];
  __shared__ float s_comb[CC*CPAD];
  __shared__ float s_A[JJ*JJ];
  __shared__ float s_dis[JJ];

  const int b = blockIdx.x, tid = threadIdx.x;
  const long bb = (long)b * (CC*TT);
  float* s_xs = s_comb;
  float* s_Mt = s_kv;

  if (tid < JJ) {
    float dsum = 0.f;
    for (int i = 0; i < JJ; ++i) dsum += adj[tid*JJ + i];
    s_dis[tid] = dsum > 0.f ? rsqrtf(dsum) : 0.f;
  }
  for (int o = tid; o < CC*TT; o += 128) s_xs[o] = x[bb + o];
  for (int o = tid; o < TT*TT; o += 128) {
    int f = o / TT, t = o - f*TT;
    s_Mt[t*TT + f] = tadj[o] * tmask[o];
  }
  __syncthreads();
  for (int o = tid; o < JJ*JJ; o += 128) {
    int v = o / JJ, j = o - v*JJ;
    s_A[o] = sadj[o] * adj[o] * s_dis[v] * s_dis[j];
  }
  __syncthreads();

  for (int o = tid; o < CC*TT; o += 128) {
    int c = o / TT, t = o - c*TT, v = c / 3, dd = c - v*3;
    float acc = 0.f;
    for (int j = 0; j < JJ; ++j) acc += s_A[v*JJ + j] * s_xs[(j*3 + dd)*TT + t];
    s_sp[o] = acc;
  }
  for (int o = tid; o < CC*TT; o += 128) {
    int n = o / TT, f = o - n*TT;
    float a0 = 0.f, a1 = 0.f;
    for (int t = 0; t < TT; t += 2) {
      a0 += s_xs[n*TT + t    ] * s_Mt[(t    )*TT + f];
      a1 += s_xs[n*TT + t + 1] * s_Mt[(t + 1)*TT + f];
    }
    s_tp[o] = a0 + a1;
  }
  __syncthreads();

  for (int o = tid; o < CC*TT; o += 128) {
    int c = o / TT, t = o - c*TT;
    s_comb[c*CPAD + t] = st_bo[c] + ts_bo[t];
  }

  {
    float* s_k = s_kv;
    float* s_v = s_kv + TT*HD;
    for (int h = 0; h < HH; ++h) {
      const int base = h*HD;
      __syncthreads();
      {
        const int d = tid & 63, krow = tid >> 6;
        for (int kk = 0; kk < CC/2; ++kk) {
          int k = kk*2 + krow;
          float aK = st_bk[base + d], aV = st_bv[base + d];
          const float* tr = s_tp + k*TT;
          for (int t = 0; t < TT; ++t) {
            float a = tr[t];
            aK += a * st_wk[(long)t*EE + base + d];
            aV += a * st_wv[(long)t*EE + base + d];
          }
          s_k[k*HD + d] = aK;
          s_v[k*HD + d] = aV;
        }
      }
      __syncthreads();
      if (tid < TT) {
        const int q = tid;
        float qv[HD];
        #pragma unroll
        for (int d = 0; d < HD; ++d) qv[d] = st_bq[base + d];
        for (int c = 0; c < CC; ++c) {
          float a = s_sp[c*TT + q];
          const float* wr = st_wq + (long)c*EE + base;
          #pragma unroll
          for (int d = 0; d < HD; ++d) qv[d] += a * wr[d];
        }
        float m = -INFINITY, l = 0.f, ov[HD];
        #pragma unroll
        for (int d = 0; d < HD; ++d) ov[d] = 0.f;
        for (int k = 0; k < CC; ++k) {
          const float4* kr4 = (const float4*)(s_k + k*HD);
          float s0=0.f,s1=0.f,s2=0.f,s3=0.f;
          #pragma unroll
          for (int i = 0; i < 16; ++i) {
            float4 kk4 = kr4[i];
            s0 += qv[4*i  ]*kk4.x; s1 += qv[4*i+1]*kk4.y;
            s2 += qv[4*i+2]*kk4.z; s3 += qv[4*i+3]*kk4.w;
          }
          float s  = (s0+s1+s2+s3) * 0.125f;
          float mn = fmaxf(m, s);
          float corr = __expf(m - mn);
          float p    = __expf(s - mn);
          l = l*corr + p;
          const float4* vr4 = (const float4*)(s_v + k*HD);
          #pragma unroll
          for (int i = 0; i < 16; ++i) {
            float4 vv4 = vr4[i];
            ov[4*i  ] = ov[4*i  ]*corr + p*vv4.x;
            ov[4*i+1] = ov[4*i+1]*corr + p*vv4.y;
            ov[4*i+2] = ov[4*i+2]*corr + p*vv4.z;
            ov[4*i+3] = ov[4*i+3]*corr + p*vv4.w;
          }
          m = mn;
        }
        float rl = 1.f/l;
        #pragma unroll
        for (int d = 0; d < HD; ++d) ov[d] *= rl;
        for (int c = 0; c < CC; ++c) {
          const float* wr = st_wo + (long)base*CC + c;
          float a0=0.f,a1=0.f,a2=0.f,a3=0.f;
          #pragma unroll
          for (int d = 0; d < HD; d += 4) {
            a0 += ov[d  ]*wr[(long)(d  )*CC]; a1 += ov[d+1]*wr[(long)(d+1)*CC];
            a2 += ov[d+2]*wr[(long)(d+2)*CC]; a3 += ov[d+3]*wr[(long)(d+3)*CC];
          }
          s_comb[c*CPAD + q] += a0+a1+a2+a3;
        }
      }
    }
  }

  {
    float* s_k = s_kv;
    float* s_v = s_kv + TT*HD;
    for (int h = 0; h < HH; ++h) {
      const int base = h*HD;
      __syncthreads();
      {
        const int d = tid & 63, krow = tid >> 6;
        for (int kk = 0; kk < TT/2; ++kk) {
          int k = kk*2 + krow;
          float aK = ts_bk[base + d], aV = ts_bv[base + d];
          for (int c = 0; c < CC; ++c) {
            float a = s_sp[c*TT + k];
            aK += a * ts_wk[(long)c*EE + base + d];
            aV += a * ts_wv[(long)c*EE + base + d];
          }
          s_k[k*HD + d] = aK;
          s_v[k*HD + d] = aV;
        }
      }
      __syncthreads();
      if (tid < CC) {
        const int q = tid;
        float qv[HD];
        #pragma unroll
        for (int d = 0; d < HD; ++d) qv[d] = ts_bq[base + d];
        const float* tr = s_tp + q*TT;
        for (int t = 0; t < TT; ++t) {
          float a = tr[t];
          const float* wr = ts_wq + (long)t*EE + base;
          #pragma unroll
          for (int d = 0; d < HD; ++d) qv[d] += a * wr[d];
        }
        float m = -INFINITY, l = 0.f, ov[HD];
        #pragma unroll
        for (int d = 0; d < HD; ++d) ov[d] = 0.f;
        for (int k = 0; k < TT; ++k) {
          const float4* kr4 = (const float4*)(s_k + k*HD);
          float s0=0.f,s1=0.f,s2=0.f,s3=0.f;
          #pragma unroll
          for (int i = 0; i < 16; ++i) {
            float4 kk4 = kr4[i];
            s0 += qv[4*i  ]*kk4.x; s1 += qv[4*i+1]*kk4.y;
            s2 += qv[4*i+2]*kk4.z; s3 += qv[4*i+3]*kk4.w;
          }
          float s  = (s0+s1+s2+s3) * 0.125f;
          float mn = fmaxf(m, s);
          float corr = __expf(m - mn);
          float p    = __expf(s - mn);
          l = l*corr + p;
          const float4* vr4 = (const float4*)(s_v + k*HD);
          #pragma unroll
          for (int i = 0; i < 16; ++i) {
            float4 vv4 = vr4[i];
            ov[4*i  ] = ov[4*i  ]*corr + p*vv4.x;
            ov[4*i+1] = ov[4*i+1]*corr + p*vv4.y;
            ov[4*i+2] = ov[4*i+2]*corr + p*vv4.z;
            ov[4*i+3] = ov[4*i+3]*corr + p*vv4.w;
          }
          m = mn;
        }
        float rl = 1.f/l;
        #pragma unroll
        for (int d = 0; d < HD; ++d) ov[d] *= rl;
        for (int t = 0; t < TT; ++t) {
          const float* wr = ts_wo + (long)base*TT + t;
          float a0=0.f,a1=0.f,a2=0.f,a3=0.f;
          #pragma unroll
          for (int d = 0; d < HD; d += 4) {
            a0 += ov[d  ]*wr[(long)(d  )*TT]; a1 += ov[d+1]*wr[(long)(d+1)*TT];
            a2 += ov[d+2]*wr[(long)(d+2)*TT]; a3 += ov[d+3]*wr[(long)(d+3)*TT];
          }
          s_comb[q*CPAD + t] += a0+a1+a2+a3;
        }
      }
    }
  }
  __syncthreads();

  if (tid < TT) {
    const int t = tid;
    float mean = 0.f;
    for (int c = 0; c < CC; ++c) mean += s_comb[c*CPAD + t];
    mean *= (1.f/CC);
    float var = 0.f;
    for (int c = 0; c < CC; ++c) { float dv = s_comb[c*CPAD + t] - mean; var += dv*dv; }
    var *= (1.f/CC);
    float rstd = 1.f / sqrtf(var + 1e-5f);
    for (int c = 0; c < CC; ++c) {
      float y = (s_comb[c*CPAD + t] - mean) * rstd * alpha[c] + beta[c];
      s_comb[c*CPAD + t] = y + x[bb + c*TT + t];
    }
  }
  __syncthreads();

  float* s_w = s_kv;
  for (int o = tid; o < TT*TT; o += 128) {
    int f = o / TT, t = o - f*TT;
    s_w[t*TT + f] = fcw[o];
  }
  __syncthreads();

  for (int o = tid; o < CC*TT; o += 128) {
    int c = o / TT, f = o - c*TT;
    const float* cr = s_comb + c*CPAD;
    float a0 = 0.f, a1 = 0.f;
    for (int t = 0; t < TT; t += 2) {
      a0 += cr[t    ] * s_w[(t    )*TT + f];
      a1 += cr[t + 1] * s_w[(t + 1)*TT + f];
    }
    out[bb + o] = tanhf(a0 + a1 + fcb[f]);
  }
}

// ---------------------------------------------------------------- launch
extern "C" void kernel_launch(void* const* d_in, const int* in_sizes, int n_in,
                              void* d_out, int out_size, void* d_ws, size_t ws_size,
                              hipStream_t stream) {
  const float* x     = (const float*)d_in[0];
  const float* adj   = (const float*)d_in[1];
  const float* sadj  = (const float*)d_in[2];
  const float* tmask = (const float*)d_in[3];
  const float* tadj  = (const float*)d_in[4];
  const float* st_wq = (const float*)d_in[5];  const float* st_bq = (const float*)d_in[6];
  const float* st_wk = (const float*)d_in[7];  const float* st_bk = (const float*)d_in[8];
  const float* st_wv = (const float*)d_in[9];  const float* st_bv = (const float*)d_in[10];
  const float* st_wo = (const float*)d_in[11]; const float* st_bo = (const float*)d_in[12];
  const float* ts_wq = (const float*)d_in[13]; const float* ts_bq = (const float*)d_in[14];
  const float* ts_wk = (const float*)d_in[15]; const float* ts_bk = (const float*)d_in[16];
  const float* ts_wv = (const float*)d_in[17]; const float* ts_bv = (const float*)d_in[18];
  const float* ts_wo = (const float*)d_in[19]; const float* ts_bo = (const float*)d_in[20];
  const float* alpha = (const float*)d_in[21]; const float* beta  = (const float*)d_in[22];
  const float* fcw   = (const float*)d_in[23]; const float* fcb   = (const float*)d_in[24];
  float* out = (float*)d_out;

  const int B = in_sizes[0] / (CC*TT);
  const size_t w_bytes   = (size_t)W_TOTAL * 2 + 1024;   // + bias2 floats
  const size_t spt_bytes = (size_t)B * SPT_R * SPT_S * 2;
  const size_t tp_bytes  = (size_t)B * TP_R * TP_S * 2;
  const size_t need = w_bytes + spt_bytes + tp_bytes;

  if (ws_size >= need) {
    bf16*  wsec    = (bf16*)d_ws;
    float* bias2   = (float*)((char*)d_ws + (size_t)W_TOTAL*2);
    bf16*  spT_all = (bf16*)((char*)d_ws + w_bytes);
    bf16*  tp_all  = spT_all + (size_t)B * SPT_R * SPT_S;

    // single fused prep launch: weight prep (blocks 0..1552) + token prep
    // (blocks 1553..1553+B-1) run concurrently (no data dependence).
    k_pre<<<NWPB + B, 256, 0, stream>>>(x, adj, sadj, tmask, tadj,
                                        st_wk, st_wq, ts_wk, ts_wq,
                                        st_wv, st_wo, ts_wv, ts_wo,
                                        st_bo, st_bv, ts_bo, ts_bv,
                                        wsec, bias2, spT_all, tp_all);
    k_attn2<<<B, 1024, 0, stream>>>(spT_all, tp_all, wsec, st_bq, ts_bq,
                                    bias2, x, alpha, beta, fcw, fcb, out);
  } else {
    k_fused<<<B, 128, 0, stream>>>(x, adj, sadj, tmask, tadj,
                                   st_wq, st_bq, st_wk, st_bk, st_wv, st_bv, st_wo, st_bo,
                                   ts_wq, ts_bq, ts_wk, ts_bk, ts_wv, ts_bv, ts_wo, ts_bo,
                                   alpha, beta, fcw, fcb, out);
  }
}